// Round 4
// baseline (6552.465 us; speedup 1.0000x reference)
//
#include <hip/hip_runtime.h>
#include <cstdint>
#include <cstddef>

typedef unsigned short u16;
typedef __attribute__((ext_vector_type(8))) short short8;
typedef __attribute__((ext_vector_type(4))) float f32x4;

__device__ __forceinline__ float b2f(u16 u){ return __uint_as_float(((unsigned)u)<<16); }
__device__ __forceinline__ u16 f2b(float f){
    unsigned u = __float_as_uint(f);
    return (u16)((u + 0x7fffu + ((u>>16)&1u)) >> 16);
}
__device__ __forceinline__ int iclamp(int v, int lo, int hi){ return v<lo?lo:(v>hi?hi:v); }
__device__ __forceinline__ float san(float v){ return (v==v) ? v : 999.0f; }  // NaN fingerprint

// scalar load of an EXTERNAL input value (dtype per F32 flag at compile time)
template<bool F32>
__device__ __forceinline__ float lds_(const void* p, size_t i){
    return F32 ? ((const float*)p)[i] : b2f(((const u16*)p)[i]);
}
// 8-wide load -> bf16 fragment.  ISF32: source is f32 (convert); else raw bf16.
template<bool ISF32>
__device__ __forceinline__ short8 ld8(const void* p, size_t i){
    if(ISF32){
        const float* f = (const float*)p + i;
        f32x4 a = *(const f32x4*)f;
        f32x4 b = *(const f32x4*)(f+4);
        short8 r;
        #pragma unroll
        for(int j=0;j<4;j++){ r[j]=(short)f2b(a[j]); r[4+j]=(short)f2b(b[j]); }
        return r;
    }
    return *(const short8*)((const u16*)p + i);
}

// =============== dtype detector: 0 = bf16 inputs, 1 = f32 inputs ===============
__global__ __launch_bounds__(256) void k_detect(const void* skill_emb, int* flag){
    __shared__ int votes[256];
    const unsigned* w = (const unsigned*)skill_emb;
    int v=0;
    for(int i=threadIdx.x;i<512;i+=256){
        const unsigned lo = w[i] & 0xFFFFu;
        const unsigned e  = (lo>>7)&0xFFu;
        v += (e>=118u && e<=134u) ? 1 : 0;
    }
    votes[threadIdx.x]=v; __syncthreads();
    for(int s=128;s>0;s>>=1){ if(threadIdx.x<s) votes[threadIdx.x]+=votes[threadIdx.x+s]; __syncthreads(); }
    if(threadIdx.x==0) flag[0] = (votes[0] >= 256) ? 0 : 1;
}

// =============== generic BT GEMM: C(MxN) = A(MxK) @ B(NxK)^T (+bias), bf16 out ======
// AIN/BIN: operand is an external input (dtype per F32); else internal bf16.
template<bool TRANSOUT, bool RELU, bool AIN, bool BIN, bool F32>
__global__ __launch_bounds__(256) void gemm_bt(
    const void* __restrict__ A, const void* __restrict__ B,
    const void* __restrict__ bias, u16* __restrict__ C,
    int M, int N, int K, int ldb, int ldc, const int* __restrict__ flag)
{
    if(flag[0] != (F32?1:0)) return;
    constexpr int BM=128, BN=64, BK=32;
    __shared__ u16 As[BM][BK+8];
    __shared__ u16 Bs[BN][BK+8];
    const int tid = threadIdx.x;
    const int bm = blockIdx.x*BM, bn = blockIdx.y*BN;
    const int wave = tid>>6, lane = tid&63, lm = lane&15, lg = lane>>4;
    const int wm = (wave>>1)*64, wn = (wave&1)*32;
    f32x4 acc[4][2];
    #pragma unroll
    for(int i=0;i<4;i++){ acc[i][0]=(f32x4){0.f,0.f,0.f,0.f}; acc[i][1]=(f32x4){0.f,0.f,0.f,0.f}; }

    const int arow0 = tid>>2, akc0 = (tid&3)*8;       // rows 0..63
    const int arow1 = arow0 + 64;                      // rows 64..127
    for(int k0=0;k0<K;k0+=BK){
        *(short8*)&As[arow0][akc0] = ld8<F32&&AIN>(A, (size_t)(bm+arow0)*K + k0+akc0);
        *(short8*)&As[arow1][akc0] = ld8<F32&&AIN>(A, (size_t)(bm+arow1)*K + k0+akc0);
        *(short8*)&Bs[arow0][akc0] = ld8<F32&&BIN>(B, (size_t)(bn+arow0)*ldb + k0+akc0);
        __syncthreads();
        short8 af[4], bfg[2];
        #pragma unroll
        for(int mt=0;mt<4;mt++) af[mt]  = *(const short8*)&As[wm+mt*16+lm][lg*8];
        #pragma unroll
        for(int nt=0;nt<2;nt++) bfg[nt] = *(const short8*)&Bs[wn+nt*16+lm][lg*8];
        #pragma unroll
        for(int nt=0;nt<2;nt++)
            #pragma unroll
            for(int mt=0;mt<4;mt++)
                acc[mt][nt] = __builtin_amdgcn_mfma_f32_16x16x32_bf16(af[mt], bfg[nt], acc[mt][nt], 0,0,0);
        __syncthreads();
    }
    #pragma unroll
    for(int nt=0;nt<2;nt++){
        const int col = bn+wn+nt*16+lm;
        const float bv = bias ? lds_<F32>(bias, col) : 0.f;
        #pragma unroll
        for(int mt=0;mt<4;mt++){
            const int row0 = bm+wm+mt*16+lg*4;
            #pragma unroll
            for(int r=0;r<4;r++){
                const int row = row0+r;
                float v = acc[mt][nt][r] + bv;
                if(RELU) v = fmaxf(v, 0.f);
                const size_t idx = TRANSOUT ? ((size_t)col*ldc + row) : ((size_t)row*ldc + col);
                C[idx] = f2b(v);
            }
        }
    }
}

// =============== h1_pre = skill_emb @ gcn_w1^T   (101x8) ===============
template<bool F32>
__global__ __launch_bounds__(256) void k_h1pre(const void* __restrict__ skill_emb,
                                               const void* __restrict__ gcn_w1,
                                               float* __restrict__ h1pre,
                                               const int* __restrict__ flag)
{
    if(flag[0] != (F32?1:0)) return;
    for(int i=threadIdx.x;i<808;i+=256){
        const int n=i>>3, j=i&7;
        float acc=0.f;
        for(int k=0;k<256;k++) acc += lds_<F32>(skill_emb, n*256+k)*lds_<F32>(gcn_w1, j*256+k);
        h1pre[i]=acc;
    }
}

// =============== combo/sid index arrays, t-major [t*64+b], clamped (dtype-independent) ======
__global__ __launch_bounds__(256) void k_idx(const int* __restrict__ skill,
                                             const int* __restrict__ answer,
                                             const int* __restrict__ student,
                                             int* __restrict__ combo_t, int* __restrict__ sid_t)
{
    const int i = blockIdx.x*256 + threadIdx.x;
    if(i>=32000) return;
    const int t = i>>6, b = i&63;
    const int sk = iclamp(skill[b*500+t], 0, 100);
    const int an = iclamp(answer[b*500+t], 0, 2);
    const int sd = iclamp(student[b*500+t]-1, 0, 4095);
    combo_t[i] = sk*3+an;
    sid_t[i]   = sd;
}

// =============== per-batch skill GCN, softmax pooling -> pooled (64x256 f32) ===============
template<bool F32>
__global__ __launch_bounds__(256) void k_gcn(
    const int* __restrict__ skill, const int* __restrict__ answer,
    const void* __restrict__ pos, const float* __restrict__ h1pre,
    const void* __restrict__ gcn_b1, const void* __restrict__ gcn_w2, const void* __restrict__ gcn_b2,
    float* __restrict__ pooled, const int* __restrict__ flag)
{
    if(flag[0] != (F32?1:0)) return;
    const int b = blockIdx.x, tid = threadIdx.x;
    __shared__ int   sk[500];
    __shared__ float msk[500];
    __shared__ float coef[500];
    __shared__ float deg[101];
    __shared__ float agg1[101*8];
    __shared__ float agg2[101*8];
    __shared__ float red[256];
    __shared__ float vec8[8];
    __shared__ float sS[1];

    for(int i=tid;i<500;i+=256){
        sk[i]=iclamp(skill[b*500+i],0,100);
        msk[i] = (answer[b*500+i]!=2)?1.f:0.f;
    }
    for(int i=tid;i<101;i+=256) deg[i]=1.f;           // self loop
    if(tid<8)  vec8[tid]=0.f;
    if(tid==8) sS[0]=0.f;
    __syncthreads();
    for(int e=tid;e<499;e+=256) atomicAdd(&deg[sk[e+1]], 1.f);
    __syncthreads();
    for(int i=tid;i<101;i+=256) deg[i] = rsqrtf(deg[i]);   // deg -> dinv
    float cnt=0.f; for(int i=tid;i<500;i+=256) cnt += msk[i];
    __syncthreads();
    red[tid]=cnt; __syncthreads();
    for(int s=128;s>0;s>>=1){ if(tid<s) red[tid]+=red[tid+s]; __syncthreads(); }
    const int len = iclamp((int)(red[0]+0.5f), 1, 500);
    __syncthreads();
    // layer1 aggregate (8-dim)
    for(int i=tid;i<808;i+=256){ const int n=i>>3; agg1[i] = deg[n]*deg[n]*h1pre[i]; }
    __syncthreads();
    for(int i=tid;i<499*8;i+=256){
        const int e=i>>3, j=i&7, s=sk[e], d=sk[e+1];
        atomicAdd(&agg1[d*8+j], deg[s]*deg[d]*h1pre[s*8+j]);
    }
    __syncthreads();
    for(int i=tid;i<808;i+=256){ const int j=i&7; agg1[i] = fmaxf(agg1[i]+lds_<F32>(gcn_b1,j), 0.f); }
    __syncthreads();
    // layer2 aggregate (8-dim: W2 projection commutes with the linear scatter)
    for(int i=tid;i<808;i+=256){ const int n=i>>3; agg2[i] = deg[n]*deg[n]*agg1[i]; }
    __syncthreads();
    for(int i=tid;i<499*8;i+=256){
        const int e=i>>3, j=i&7, s=sk[e], d=sk[e+1];
        atomicAdd(&agg2[d*8+j], deg[s]*deg[d]*agg1[s*8+j]);
    }
    // softmax over all 500 positions of pos[len-1,t]*mask
    const size_t prow = (size_t)(len-1)*500;
    float vmax = -1e30f;
    for(int i=tid;i<500;i+=256){ const float v = lds_<F32>(pos, prow+i)*msk[i]; coef[i]=v; vmax=fmaxf(vmax,v); }
    red[tid]=vmax; __syncthreads();           // barrier also orders agg2 atomics before later reads
    for(int s=128;s>0;s>>=1){ if(tid<s) red[tid]=fmaxf(red[tid],red[tid+s]); __syncthreads(); }
    const float m = red[0]; __syncthreads();
    float lsum=0.f;
    for(int i=tid;i<500;i+=256){ const float e=__expf(coef[i]-m); coef[i]=e; lsum+=e; }
    red[tid]=lsum; __syncthreads();
    for(int s=128;s>0;s>>=1){ if(tid<s) red[tid]+=red[tid+s]; __syncthreads(); }
    const float inv = 1.f/red[0];
    __syncthreads();
    // vec8 = sum_t c_t*agg2[skill_t];  S = sum_t c_t   (c = softmax*mask)
    float v8[8]={0,0,0,0,0,0,0,0}; float ls=0.f;
    for(int i=tid;i<500;i+=256){
        const float ci = coef[i]*inv*msk[i];
        if(ci!=0.f){
            const int n=sk[i]; ls+=ci;
            #pragma unroll
            for(int j=0;j<8;j++) v8[j] += ci*agg2[n*8+j];
        }
    }
    #pragma unroll
    for(int j=0;j<8;j++) atomicAdd(&vec8[j], v8[j]);
    atomicAdd(&sS[0], ls);
    __syncthreads();
    {   // pooled[b,c] = vec8 . W2[c] + b2[c]*S
        const int o = tid;
        float acc = lds_<F32>(gcn_b2,o)*sS[0];
        #pragma unroll
        for(int j=0;j<8;j++) acc += vec8[j]*lds_<F32>(gcn_w2, o*8+j);
        pooled[b*256+o] = acc;
    }
}

// ====== x-part tables: table[combo] = x(skill,answer) @ Wih[:,256:768]^T + bih + bhh ======
template<bool F32>
__global__ __launch_bounds__(256) void k_table(
    const void* __restrict__ skill_emb, const void* __restrict__ answer_emb,
    const void* __restrict__ wih, const void* __restrict__ bih, const void* __restrict__ bhh,
    float* __restrict__ table, const int* __restrict__ flag)
{
    if(flag[0] != (F32?1:0)) return;
    const int combo = blockIdx.x, tid = threadIdx.x;
    const int sid = combo/3, ans = combo - sid*3;
    __shared__ float sf[256], sg[256];
    const size_t se = (size_t)sid*256, ae = (size_t)ans*256;
    sf[tid] = (ans==1) ? lds_<F32>(skill_emb, se+tid) : lds_<F32>(answer_emb, ae+tid);
    sg[tid] = (ans==1) ? lds_<F32>(answer_emb, ae+tid) : lds_<F32>(skill_emb, se+tid);
    __syncthreads();
    const int o = tid;
    float acc = lds_<F32>(bih,o) + lds_<F32>(bhh,o);
    const size_t w = (size_t)o*768;
    for(int k=0;k<256;k++)
        acc += sf[k]*lds_<F32>(wih, w+256+k) + sg[k]*lds_<F32>(wih, w+512+k);
    table[(size_t)combo*256 + o] = acc;
}

// =============== pooled_proj[b] = pooled[b] @ dg_wih[:, :256]^T  (bf16 64x256) ===============
template<bool F32>
__global__ __launch_bounds__(256) void k_pooledproj(const float* __restrict__ pooled,
                                                    const void* __restrict__ wih,
                                                    u16* __restrict__ outp,
                                                    const int* __restrict__ flag)
{
    if(flag[0] != (F32?1:0)) return;
    const int b=blockIdx.x, tid=threadIdx.x;
    __shared__ float p[256];
    p[tid] = pooled[b*256+tid];
    __syncthreads();
    const size_t w = (size_t)tid*768;
    float acc=0.f;
    for(int k=0;k<256;k++) acc += p[k]*lds_<F32>(wih, w+k);
    outp[b*256+tid]=f2b(acc);
}

// =============== fully fused: both RNNs + theta + class-gather outputs ===============
// grid 4 (16 batch rows), block 512 (8 waves).
template<bool F32>
__global__ __launch_bounds__(512) void k_rnnfused(
    const int* __restrict__ skill,
    const int* __restrict__ combo_t, const int* __restrict__ sid_t,
    const u16* __restrict__ pooled_proj, const u16* __restrict__ stu_proj,
    const float* __restrict__ table_dg, const float* __restrict__ table_hg,
    const void* __restrict__ whh_dg, const void* __restrict__ whh_hg,
    const void* __restrict__ w1_w, const void* __restrict__ w1_b,
    const void* __restrict__ w2_w, const void* __restrict__ w2_b,
    const void* __restrict__ fc_h_w, const void* __restrict__ fc_h_b,
    const void* __restrict__ fc_d_w, const void* __restrict__ fc_d_b,
    const void* __restrict__ fc_e_w, const void* __restrict__ fc_e_b,
    void* __restrict__ outp, const int* __restrict__ flag)
{
    if(flag[0] != (F32?1:0)) return;
    __shared__ u16 hD[2][16][264];
    __shared__ u16 hH[2][16][264];
    __shared__ u16 thS[16][264];
    const int rb = blockIdx.x*16;
    const int tid = threadIdx.x, wave = tid>>6, lane = tid&63;
    const int lm = lane&15, lg = lane>>4;
    for(int i=tid;i<2*16*264;i+=512){ ((u16*)hD)[i]=0; ((u16*)hH)[i]=0; }
    __syncthreads();

    const int rnn = wave>>2;
    const int colbase = (wave&3)*64;
    const void*  Wrec = rnn? whh_hg : whh_dg;
    const float* tab = rnn? table_hg : table_dg;
    const int tcb = wave*32;            // theta col base
    const int cm = tid>>5, cl = tid&31; // phase C: row, lane-in-group

    int cur = 0;
    for(int t=0;t<500;t++){
        // ---------- phase A: recurrence ----------
        {
            f32x4 acc[4];
            #pragma unroll
            for(int nt=0;nt<4;nt++) acc[nt]=(f32x4){0.f,0.f,0.f,0.f};
            #pragma unroll
            for(int kk=0;kk<8;kk++){
                short8 a = rnn ? *(const short8*)&hH[cur][lm][kk*32+lg*8]
                               : *(const short8*)&hD[cur][lm][kk*32+lg*8];
                #pragma unroll
                for(int nt=0;nt<4;nt++){
                    short8 bf = ld8<F32>(Wrec, (size_t)(colbase+nt*16+lm)*256 + kk*32 + lg*8);
                    acc[nt] = __builtin_amdgcn_mfma_f32_16x16x32_bf16(a, bf, acc[nt], 0,0,0);
                }
            }
            #pragma unroll
            for(int r=0;r<4;r++){
                const int m = lg*4+r, b = rb+m;
                const int cmb = combo_t[t*64+b];
                const float* trow = tab + (size_t)cmb*256;
                const u16*  prow = rnn ? (stu_proj + (size_t)sid_t[t*64+b]*256)
                                       : (pooled_proj + (size_t)b*256);
                #pragma unroll
                for(int nt=0;nt<4;nt++){
                    const int col = colbase+nt*16+lm;
                    const float v = acc[nt][r] + trow[col] + b2f(prow[col]);
                    const float e = __expf(2.f*v);
                    const u16 hb = f2b(1.f - 2.f/(e+1.f));   // tanh
                    if(rnn) hH[cur^1][m][col] = hb; else hD[cur^1][m][col] = hb;
                }
            }
        }
        __syncthreads();
        // ---------- phase B: theta ----------
        {
            f32x4 acc[2];
            acc[0]=(f32x4){0.f,0.f,0.f,0.f}; acc[1]=(f32x4){0.f,0.f,0.f,0.f};
            #pragma unroll
            for(int kk=0;kk<8;kk++){
                short8 aH = *(const short8*)&hH[cur^1][lm][kk*32+lg*8];
                short8 aD = *(const short8*)&hD[cur^1][lm][kk*32+lg*8];
                #pragma unroll
                for(int nt=0;nt<2;nt++){
                    const size_t wr = (size_t)(tcb+nt*16+lm)*256 + kk*32 + lg*8;
                    short8 b1 = ld8<F32>(w1_w, wr);
                    short8 b2v= ld8<F32>(w2_w, wr);
                    acc[nt] = __builtin_amdgcn_mfma_f32_16x16x32_bf16(aH, b1,  acc[nt], 0,0,0);
                    acc[nt] = __builtin_amdgcn_mfma_f32_16x16x32_bf16(aD, b2v, acc[nt], 0,0,0);
                }
            }
            #pragma unroll
            for(int nt=0;nt<2;nt++){
                const int col = tcb+nt*16+lm;
                const float bb = lds_<F32>(w1_b,col) + lds_<F32>(w2_b,col);
                #pragma unroll
                for(int r=0;r<4;r++){
                    const float x = acc[nt][r] + bb;
                    thS[lg*4+r][col] = f2b(1.f/(1.f+__expf(-x)));
                }
            }
        }
        __syncthreads();
        // ---------- phase C: outputs (position t predicts class at t+1) ----------
        if(t<499){
            const int b = rb+cm;
            const int ns = skill[b*500 + t + 1];
            float w0=0.f, w1v=0.f, w2x=0.f;
            bool valid = (ns != 100);
            if(valid){
                const int c = iclamp(ns, 0, 99);
                const int k = cl*8;
                float o0=0.f,o1=0.f,o2=0.f;
                #pragma unroll
                for(int j=0;j<8;j++){
                    const float hh = b2f(hH[cur^1][cm][k+j]);
                    const float hd = b2f(hD[cur^1][cm][k+j]);
                    const float th = b2f(thS[cm][k+j]);
                    o0 += hh*lds_<F32>(fc_h_w,(size_t)c*256+k+j);
                    o1 += hd*lds_<F32>(fc_d_w,(size_t)c*256+k+j);
                    o2 += th*hh*lds_<F32>(fc_e_w,(size_t)c*512+k+j)
                        + (1.f-th)*hd*lds_<F32>(fc_e_w,(size_t)c*512+256+k+j);
                }
                #pragma unroll
                for(int off=16;off>0;off>>=1){
                    o0 += __shfl_down(o0,off,32);
                    o1 += __shfl_down(o1,off,32);
                    o2 += __shfl_down(o2,off,32);
                }
                w0  = o0 + lds_<F32>(fc_h_b,c);
                w1v = o1 + lds_<F32>(fc_d_b,c);
                w2x = o2 + lds_<F32>(fc_e_b,c);
            }
            if(cl==0){
                const float v0 = valid? san(w0) :0.f, v1 = valid? san(w1v):0.f, v2 = valid? san(w2x):0.f;
                if(F32){
                    ((float*)outp)[          b*499+t] = v0;
                    ((float*)outp)[31936   + b*499+t] = v1;
                    ((float*)outp)[2*31936 + b*499+t] = v2;
                }else{
                    ((u16*)outp)[          b*499+t] = f2b(v0);
                    ((u16*)outp)[31936   + b*499+t] = f2b(v1);
                    ((u16*)outp)[2*31936 + b*499+t] = f2b(v2);
                }
            }
        }
        __syncthreads();
        cur ^= 1;
    }
}

// ================================= launch =================================
extern "C" void kernel_launch(void* const* d_in, const int* in_sizes, int n_in,
                              void* d_out, int out_size, void* d_ws, size_t ws_size,
                              hipStream_t stream)
{
    const int* student = (const int*)d_in[0];
    const int* skill   = (const int*)d_in[1];
    const int* answer  = (const int*)d_in[2];
    const void* G        = d_in[3];
    const void* skill_emb= d_in[4];
    const void* answer_emb=d_in[5];
    const void* stu      = d_in[6];
    const void* hg_w1    = d_in[7];
    const void* hg_b1    = d_in[8];
    const void* hg_w2    = d_in[9];
    const void* hg_b2    = d_in[10];
    const void* gcn_w1   = d_in[11];
    const void* gcn_b1   = d_in[12];
    const void* gcn_w2   = d_in[13];
    const void* gcn_b2   = d_in[14];
    const void* w1_w     = d_in[15];
    const void* w1_b     = d_in[16];
    const void* w2_w     = d_in[17];
    const void* w2_b     = d_in[18];
    const void* fc_d_w   = d_in[19];
    const void* fc_d_b   = d_in[20];
    const void* fc_h_w   = d_in[21];
    const void* fc_h_b   = d_in[22];
    const void* fc_e_w   = d_in[23];
    const void* fc_e_b   = d_in[24];
    const void* pos      = d_in[25];
    const void* dg_wih   = d_in[26];
    const void* dg_whh   = d_in[27];
    const void* dg_bih   = d_in[28];
    const void* dg_bhh   = d_in[29];
    const void* hgr_wih  = d_in[30];
    const void* hgr_whh  = d_in[31];
    const void* hgr_bih  = d_in[32];
    const void* hgr_bhh  = d_in[33];

    char* ws = (char*)d_ws;
    size_t off = 0;
    auto nxt = [&](size_t bytes)->char*{
        char* r = ws + off;
        off += (bytes + 255) & ~(size_t)255;
        return r;
    };
    int*   flag       = (int*)  nxt(4);
    float* h1pre      = (float*)nxt(808*4);
    float* pooled     = (float*)nxt(64*256*4);
    float* table_dg   = (float*)nxt(303*256*4);
    float* table_hg   = (float*)nxt(303*256*4);
    u16*   tmpT       = (u16*)  nxt((size_t)256*4096*2);
    u16*   hbuf       = (u16*)  nxt((size_t)4096*256*2);
    u16*   stu_proj   = (u16*)  nxt((size_t)4096*256*2);
    u16*   pooled_proj= (u16*)  nxt(64*256*2);
    int*   combo_t    = (int*)  nxt(32000*4);
    int*   sid_t      = (int*)  nxt(32000*4);
    const size_t used = off;   // ~7.3 MB

    hipMemsetAsync(d_ws, 0, used, stream);
    k_detect<<<1,256,0,stream>>>(skill_emb, flag);
    k_idx<<<125,256,0,stream>>>(skill, answer, student, combo_t, sid_t);

    #define BOTH(launchexpr_bf16, launchexpr_f32) launchexpr_bf16; launchexpr_f32;

    // small prep
    BOTH((k_h1pre<false><<<1,256,0,stream>>>(skill_emb, gcn_w1, h1pre, flag)),
         (k_h1pre<true ><<<1,256,0,stream>>>(skill_emb, gcn_w1, h1pre, flag)));
    BOTH((k_gcn<false><<<64,256,0,stream>>>(skill, answer, pos, h1pre, gcn_b1, gcn_w2, gcn_b2, pooled, flag)),
         (k_gcn<true ><<<64,256,0,stream>>>(skill, answer, pos, h1pre, gcn_b1, gcn_w2, gcn_b2, pooled, flag)));
    BOTH((k_table<false><<<303,256,0,stream>>>(skill_emb, answer_emb, dg_wih,  dg_bih,  dg_bhh,  table_dg, flag)),
         (k_table<true ><<<303,256,0,stream>>>(skill_emb, answer_emb, dg_wih,  dg_bih,  dg_bhh,  table_dg, flag)));
    BOTH((k_table<false><<<303,256,0,stream>>>(skill_emb, answer_emb, hgr_wih, hgr_bih, hgr_bhh, table_hg, flag)),
         (k_table<true ><<<303,256,0,stream>>>(skill_emb, answer_emb, hgr_wih, hgr_bih, hgr_bhh, table_hg, flag)));

    // student GCN chain over dense G  (outputs internal bf16)
    BOTH((gemm_bt<true ,false,true ,true ,false><<<dim3(32,4),256,0,stream>>>(stu,  hg_w1, hg_b1, tmpT, 4096,256,256,  256, 4096, flag)),
         (gemm_bt<true ,false,true ,true ,true ><<<dim3(32,4),256,0,stream>>>(stu,  hg_w1, hg_b1, tmpT, 4096,256,256,  256, 4096, flag)));
    BOTH((gemm_bt<false,true ,true ,false,false><<<dim3(32,4),256,0,stream>>>(G,    tmpT,  nullptr, hbuf, 4096,256,4096, 4096, 256, flag)),
         (gemm_bt<false,true ,true ,false,true ><<<dim3(32,4),256,0,stream>>>(G,    tmpT,  nullptr, hbuf, 4096,256,4096, 4096, 256, flag)));
    BOTH((gemm_bt<true ,false,false,true ,false><<<dim3(32,4),256,0,stream>>>(hbuf, hg_w2, hg_b2, tmpT, 4096,256,256,  256, 4096, flag)),
         (gemm_bt<true ,false,false,true ,true ><<<dim3(32,4),256,0,stream>>>(hbuf, hg_w2, hg_b2, tmpT, 4096,256,256,  256, 4096, flag)));
    BOTH((gemm_bt<false,false,true ,false,false><<<dim3(32,4),256,0,stream>>>(G,    tmpT,  nullptr, hbuf, 4096,256,4096, 4096, 256, flag)),
         (gemm_bt<false,false,true ,false,true ><<<dim3(32,4),256,0,stream>>>(G,    tmpT,  nullptr, hbuf, 4096,256,4096, 4096, 256, flag)));
    BOTH((gemm_bt<false,false,false,true ,false><<<dim3(32,4),256,0,stream>>>(hbuf, hgr_wih, nullptr, stu_proj, 4096,256,256, 768, 256, flag)),
         (gemm_bt<false,false,false,true ,true ><<<dim3(32,4),256,0,stream>>>(hbuf, hgr_wih, nullptr, stu_proj, 4096,256,256, 768, 256, flag)));

    BOTH((k_pooledproj<false><<<64,256,0,stream>>>(pooled, dg_wih, pooled_proj, flag)),
         (k_pooledproj<true ><<<64,256,0,stream>>>(pooled, dg_wih, pooled_proj, flag)));

    // fused RNNs + theta + outputs
    BOTH((k_rnnfused<false><<<4,512,0,stream>>>(skill, combo_t, sid_t, pooled_proj, stu_proj,
                                   table_dg, table_hg, dg_whh, hgr_whh,
                                   w1_w, w1_b, w2_w, w2_b,
                                   fc_h_w, fc_h_b, fc_d_w, fc_d_b, fc_e_w, fc_e_b,
                                   d_out, flag)),
         (k_rnnfused<true ><<<4,512,0,stream>>>(skill, combo_t, sid_t, pooled_proj, stu_proj,
                                   table_dg, table_hg, dg_whh, hgr_whh,
                                   w1_w, w1_b, w2_w, w2_b,
                                   fc_h_w, fc_h_b, fc_d_w, fc_d_b, fc_e_w, fc_e_b,
                                   d_out, flag)));
    #undef BOTH
}

// Round 5
// 1752.900 us; speedup vs baseline: 3.7381x; 3.7381x over previous
//
#include <hip/hip_runtime.h>
#include <cstdint>
#include <cstddef>

typedef unsigned short u16;
typedef __attribute__((ext_vector_type(8))) short short8;
typedef __attribute__((ext_vector_type(4))) short short4v;
typedef __attribute__((ext_vector_type(4))) float f32x4;

__device__ __forceinline__ float b2f(u16 u){ return __uint_as_float(((unsigned)u)<<16); }
__device__ __forceinline__ u16 f2b(float f){
    unsigned u = __float_as_uint(f);
    return (u16)((u + 0x7fffu + ((u>>16)&1u)) >> 16);
}
__device__ __forceinline__ int iclamp(int v, int lo, int hi){ return v<lo?lo:(v>hi?hi:v); }

// 8-wide f32 -> bf16 fragment
__device__ __forceinline__ short8 ld8f(const float* p){
    f32x4 a = *(const f32x4*)p;
    f32x4 b = *(const f32x4*)(p+4);
    short8 r;
    #pragma unroll
    for(int j=0;j<4;j++){ r[j]=(short)f2b(a[j]); r[4+j]=(short)f2b(b[j]); }
    return r;
}
__device__ __forceinline__ short8 ld8b(const u16* p){ return *(const short8*)p; }

// =============== generic BT GEMM: C(MxN) = A(MxK) @ B(NxK)^T (+bias f32), bf16 out ===
// grid (M/128, N/64), block 256.
template<bool TRANSOUT, bool RELU, bool AF32, bool BF32>
__global__ __launch_bounds__(256) void gemm_bt(
    const void* __restrict__ A, const void* __restrict__ B,
    const float* __restrict__ bias, u16* __restrict__ C,
    int M, int N, int K, int ldb, int ldc)
{
    constexpr int BM=128, BN=64, BK=32;
    __shared__ u16 As[BM][BK+8];
    __shared__ u16 Bs[BN][BK+8];
    const int tid = threadIdx.x;
    const int bm = blockIdx.x*BM, bn = blockIdx.y*BN;
    const int wave = tid>>6, lane = tid&63, lm = lane&15, lg = lane>>4;
    const int wm = (wave>>1)*64, wn = (wave&1)*32;
    f32x4 acc[4][2];
    #pragma unroll
    for(int i=0;i<4;i++){ acc[i][0]=(f32x4){0.f,0.f,0.f,0.f}; acc[i][1]=(f32x4){0.f,0.f,0.f,0.f}; }

    const int arow0 = tid>>2, akc0 = (tid&3)*8;  // rows 0..63
    const int arow1 = arow0 + 64;                 // rows 64..127
    for(int k0=0;k0<K;k0+=BK){
        *(short8*)&As[arow0][akc0] = AF32 ? ld8f((const float*)A + (size_t)(bm+arow0)*K + k0+akc0)
                                          : ld8b((const u16*)A + (size_t)(bm+arow0)*K + k0+akc0);
        *(short8*)&As[arow1][akc0] = AF32 ? ld8f((const float*)A + (size_t)(bm+arow1)*K + k0+akc0)
                                          : ld8b((const u16*)A + (size_t)(bm+arow1)*K + k0+akc0);
        *(short8*)&Bs[arow0][akc0] = BF32 ? ld8f((const float*)B + (size_t)(bn+arow0)*ldb + k0+akc0)
                                          : ld8b((const u16*)B + (size_t)(bn+arow0)*ldb + k0+akc0);
        __syncthreads();
        short8 af[4], bfg[2];
        #pragma unroll
        for(int mt=0;mt<4;mt++) af[mt]  = *(const short8*)&As[wm+mt*16+lm][lg*8];
        #pragma unroll
        for(int nt=0;nt<2;nt++) bfg[nt] = *(const short8*)&Bs[wn+nt*16+lm][lg*8];
        #pragma unroll
        for(int nt=0;nt<2;nt++)
            #pragma unroll
            for(int mt=0;mt<4;mt++)
                acc[mt][nt] = __builtin_amdgcn_mfma_f32_16x16x32_bf16(af[mt], bfg[nt], acc[mt][nt], 0,0,0);
        __syncthreads();
    }
    #pragma unroll
    for(int nt=0;nt<2;nt++){
        const int col = bn+wn+nt*16+lm;
        const float bv = bias ? bias[col] : 0.f;
        #pragma unroll
        for(int mt=0;mt<4;mt++){
            const int row0 = bm+wm+mt*16+lg*4;
            #pragma unroll
            for(int r=0;r<4;r++){
                const int row = row0+r;
                float v = acc[mt][nt][r] + bv;
                if(RELU) v = fmaxf(v, 0.f);
                const size_t idx = TRANSOUT ? ((size_t)col*ldc + row) : ((size_t)row*ldc + col);
                C[idx] = f2b(v);
            }
        }
    }
}

// =============== h1_pre = skill_emb @ gcn_w1^T   (101x8, f32 in/out) ===============
__global__ __launch_bounds__(256) void k_h1pre(const float* __restrict__ skill_emb,
                                               const float* __restrict__ gcn_w1,
                                               float* __restrict__ h1pre)
{
    for(int i=threadIdx.x;i<808;i+=256){
        const int n=i>>3, j=i&7;
        float acc=0.f;
        for(int k=0;k<256;k++) acc += skill_emb[n*256+k]*gcn_w1[j*256+k];
        h1pre[i]=acc;
    }
}

// =============== combo/sid index arrays, t-major [t*64+b], clamped ===============
__global__ __launch_bounds__(256) void k_idx(const int* __restrict__ skill,
                                             const int* __restrict__ answer,
                                             const int* __restrict__ student,
                                             int* __restrict__ combo_t, int* __restrict__ sid_t)
{
    const int i = blockIdx.x*256 + threadIdx.x;
    if(i>=32000) return;
    const int t = i>>6, b = i&63;
    const int sk = iclamp(skill[b*500+t], 0, 100);
    const int an = iclamp(answer[b*500+t], 0, 2);
    const int sd = iclamp(student[b*500+t]-1, 0, 4095);
    combo_t[i] = sk*3+an;
    sid_t[i]   = sd;
}

// =============== per-batch skill GCN, softmax pooling -> pooled (64x256 f32) ===============
__global__ __launch_bounds__(256) void k_gcn(
    const int* __restrict__ skill, const int* __restrict__ answer,
    const float* __restrict__ pos, const float* __restrict__ h1pre,
    const float* __restrict__ gcn_b1, const float* __restrict__ gcn_w2, const float* __restrict__ gcn_b2,
    float* __restrict__ pooled)
{
    const int b = blockIdx.x, tid = threadIdx.x;
    __shared__ int   sk[500];
    __shared__ float msk[500];
    __shared__ float coef[500];
    __shared__ float deg[101];
    __shared__ float agg1[101*8];
    __shared__ float agg2[101*8];
    __shared__ float red[256];
    __shared__ float vec8[8];
    __shared__ float sS[1];

    for(int i=tid;i<500;i+=256){
        sk[i]=iclamp(skill[b*500+i],0,100);
        msk[i] = (answer[b*500+i]!=2)?1.f:0.f;
    }
    for(int i=tid;i<101;i+=256) deg[i]=1.f;           // self loop
    if(tid<8)  vec8[tid]=0.f;
    if(tid==8) sS[0]=0.f;
    __syncthreads();
    for(int e=tid;e<499;e+=256) atomicAdd(&deg[sk[e+1]], 1.f);
    __syncthreads();
    for(int i=tid;i<101;i+=256) deg[i] = rsqrtf(deg[i]);   // deg -> dinv
    float cnt=0.f; for(int i=tid;i<500;i+=256) cnt += msk[i];
    __syncthreads();
    red[tid]=cnt; __syncthreads();
    for(int s=128;s>0;s>>=1){ if(tid<s) red[tid]+=red[tid+s]; __syncthreads(); }
    const int len = iclamp((int)(red[0]+0.5f), 1, 500);
    __syncthreads();
    for(int i=tid;i<808;i+=256){ const int n=i>>3; agg1[i] = deg[n]*deg[n]*h1pre[i]; }
    __syncthreads();
    for(int i=tid;i<499*8;i+=256){
        const int e=i>>3, j=i&7, s=sk[e], d=sk[e+1];
        atomicAdd(&agg1[d*8+j], deg[s]*deg[d]*h1pre[s*8+j]);
    }
    __syncthreads();
    for(int i=tid;i<808;i+=256){ const int j=i&7; agg1[i] = fmaxf(agg1[i]+gcn_b1[j], 0.f); }
    __syncthreads();
    for(int i=tid;i<808;i+=256){ const int n=i>>3; agg2[i] = deg[n]*deg[n]*agg1[i]; }
    __syncthreads();
    for(int i=tid;i<499*8;i+=256){
        const int e=i>>3, j=i&7, s=sk[e], d=sk[e+1];
        atomicAdd(&agg2[d*8+j], deg[s]*deg[d]*agg1[s*8+j]);
    }
    const size_t prow = (size_t)(len-1)*500;
    float vmax = -1e30f;
    for(int i=tid;i<500;i+=256){ const float v = pos[prow+i]*msk[i]; coef[i]=v; vmax=fmaxf(vmax,v); }
    red[tid]=vmax; __syncthreads();           // also orders agg2 atomics
    for(int s=128;s>0;s>>=1){ if(tid<s) red[tid]=fmaxf(red[tid],red[tid+s]); __syncthreads(); }
    const float m = red[0]; __syncthreads();
    float lsum=0.f;
    for(int i=tid;i<500;i+=256){ const float e=__expf(coef[i]-m); coef[i]=e; lsum+=e; }
    red[tid]=lsum; __syncthreads();
    for(int s=128;s>0;s>>=1){ if(tid<s) red[tid]+=red[tid+s]; __syncthreads(); }
    const float inv = 1.f/red[0];
    __syncthreads();
    float v8[8]={0,0,0,0,0,0,0,0}; float ls=0.f;
    for(int i=tid;i<500;i+=256){
        const float ci = coef[i]*inv*msk[i];
        if(ci!=0.f){
            const int n=sk[i]; ls+=ci;
            #pragma unroll
            for(int j=0;j<8;j++) v8[j] += ci*agg2[n*8+j];
        }
    }
    #pragma unroll
    for(int j=0;j<8;j++) atomicAdd(&vec8[j], v8[j]);
    atomicAdd(&sS[0], ls);
    __syncthreads();
    {
        const int o = tid;
        float acc = gcn_b2[o]*sS[0];
        #pragma unroll
        for(int j=0;j<8;j++) acc += vec8[j]*gcn_w2[o*8+j];
        pooled[b*256+o] = acc;
    }
}

// ====== x-part tables: table[combo] = x(skill,answer) @ Wih[:,256:768]^T + bih + bhh ======
__global__ __launch_bounds__(256) void k_table(
    const float* __restrict__ skill_emb, const float* __restrict__ answer_emb,
    const float* __restrict__ wih, const float* __restrict__ bih, const float* __restrict__ bhh,
    float* __restrict__ table)
{
    const int combo = blockIdx.x, tid = threadIdx.x;
    const int sid = combo/3, ans = combo - sid*3;
    __shared__ float sf[256], sg[256];
    sf[tid] = (ans==1) ? skill_emb[(size_t)sid*256+tid] : answer_emb[(size_t)ans*256+tid];
    sg[tid] = (ans==1) ? answer_emb[(size_t)ans*256+tid] : skill_emb[(size_t)sid*256+tid];
    __syncthreads();
    const int o = tid;
    float acc = bih[o] + bhh[o];
    const float* w = wih + (size_t)o*768;
    for(int k=0;k<256;k++) acc += sf[k]*w[256+k] + sg[k]*w[512+k];
    table[(size_t)combo*256 + o] = acc;
}

// =============== pooled_proj[b] = pooled[b] @ dg_wih[:, :256]^T  (bf16 64x256) ===============
__global__ __launch_bounds__(256) void k_pooledproj(const float* __restrict__ pooled,
                                                    const float* __restrict__ wih,
                                                    u16* __restrict__ outp)
{
    const int b=blockIdx.x, tid=threadIdx.x;
    __shared__ float p[256];
    p[tid] = pooled[b*256+tid];
    __syncthreads();
    const float* w = wih + (size_t)tid*768;
    float acc=0.f;
    for(int k=0;k<256;k++) acc += p[k]*w[k];
    outp[b*256+tid]=f2b(acc);
}

// =============== RNN: 8 blocks = (rnn, 16-row group), 8 waves, Whh register-resident ======
__global__ __launch_bounds__(512) void k_rnn(
    const int* __restrict__ combo_t, const int* __restrict__ sid_t,
    const u16* __restrict__ pooled_proj, const u16* __restrict__ stu_proj,
    const float* __restrict__ table_dg, const float* __restrict__ table_hg,
    const float* __restrict__ whh_dg, const float* __restrict__ whh_hg,
    u16* __restrict__ hall_dg, u16* __restrict__ hall_hg)
{
    __shared__ u16 hl[2][16][264];
    const int bid = blockIdx.x;
    const int rnn = bid>>2, grp = bid&3, rb = grp*16;
    const float* W   = rnn ? whh_hg  : whh_dg;
    const float* tab = rnn ? table_hg: table_dg;
    u16*         out = rnn ? hall_hg : hall_dg;
    const int tid = threadIdx.x, wave = tid>>6, lane = tid&63;
    const int lm = lane&15, lg = lane>>4;
    const int cb = wave*32;

    // Whh fragments resident in registers (converted f32->bf16 once)
    short8 bw[2][8];
    #pragma unroll
    for(int nt=0;nt<2;nt++)
        #pragma unroll
        for(int kk=0;kk<8;kk++)
            bw[nt][kk] = ld8f(W + (size_t)(cb+nt*16+lm)*256 + kk*32 + lg*8);

    for(int i=tid;i<2*16*264;i+=512) ((u16*)hl)[i]=0;

    // index pipeline: slot p holds step (t) indices where p = t&1
    int cmbS[2][4], sidS[2][4];
    #pragma unroll
    for(int r=0;r<4;r++){
        const int brow = rb+lg*4+r;
        cmbS[0][r]=combo_t[brow];        sidS[0][r]=sid_t[brow];
        cmbS[1][r]=combo_t[64+brow];     sidS[1][r]=sid_t[64+brow];
    }
    // pv for t=0
    float pv[2][4];
    #pragma unroll
    for(int r=0;r<4;r++){
        const int brow = rb+lg*4+r;
        const float* trow = tab + (size_t)cmbS[0][r]*256;
        const u16*  prow = rnn ? (stu_proj + (size_t)sidS[0][r]*256)
                               : (pooled_proj + (size_t)brow*256);
        pv[0][r] = trow[cb+lm]    + b2f(prow[cb+lm]);
        pv[1][r] = trow[cb+16+lm] + b2f(prow[cb+16+lm]);
    }
    __syncthreads();

    int cur = 0;
    for(int t=0;t<500;t++){
        // recurrence MFMA (weights in registers, h from LDS)
        f32x4 acc0 = {0.f,0.f,0.f,0.f}, acc1 = {0.f,0.f,0.f,0.f};
        #pragma unroll
        for(int kk=0;kk<8;kk++){
            short8 a = *(const short8*)&hl[cur][lm][kk*32+lg*8];
            acc0 = __builtin_amdgcn_mfma_f32_16x16x32_bf16(a, bw[0][kk], acc0, 0,0,0);
            acc1 = __builtin_amdgcn_mfma_f32_16x16x32_bf16(a, bw[1][kk], acc1, 0,0,0);
        }
        // prefetch next step's pre-activation gather (indices already resident)
        float pvn[2][4];
        if(t<499){
            const int p = (t+1)&1;
            #pragma unroll
            for(int r=0;r<4;r++){
                const int brow = rb+lg*4+r;
                const float* trow = tab + (size_t)cmbS[p][r]*256;
                const u16*  prow = rnn ? (stu_proj + (size_t)sidS[p][r]*256)
                                       : (pooled_proj + (size_t)brow*256);
                pvn[0][r] = trow[cb+lm]    + b2f(prow[cb+lm]);
                pvn[1][r] = trow[cb+16+lm] + b2f(prow[cb+16+lm]);
            }
        }
        // refill index slot (t&1) with step t+2
        if(t<498){
            const int p = t&1;
            #pragma unroll
            for(int r=0;r<4;r++){
                const int brow = (t+2)*64 + rb+lg*4+r;
                cmbS[p][r]=combo_t[brow]; sidS[p][r]=sid_t[brow];
            }
        }
        // epilogue: tanh, write LDS (next buffer) + global hall
        #pragma unroll
        for(int nt=0;nt<2;nt++)
            #pragma unroll
            for(int r=0;r<4;r++){
                const int m = lg*4+r;
                const int col = cb+nt*16+lm;
                const float v = (nt? acc1[r] : acc0[r]) + pv[nt][r];
                const float e = __expf(2.f*v);
                const u16 hb = f2b(1.f - 2.f/(e+1.f));   // tanh
                hl[cur^1][m][col] = hb;
                out[((size_t)t*64 + rb+m)*256 + col] = hb;
            }
        __syncthreads();
        #pragma unroll
        for(int nt=0;nt<2;nt++)
            #pragma unroll
            for(int r=0;r<4;r++) pv[nt][r]=pvn[nt][r];
        cur ^= 1;
    }
}

// ====== theta = sigmoid(h_hg@w1^T + h_dg@w2^T + b1 + b2), dual-GEMM fused, bf16 out ======
// grid (250, 4), block 256.  M=32000, N=256, K=256.
__global__ __launch_bounds__(256) void k_theta(
    const u16* __restrict__ Ah, const u16* __restrict__ Ad,
    const float* __restrict__ w1, const float* __restrict__ w2,
    const float* __restrict__ b1, const float* __restrict__ b2,
    u16* __restrict__ theta)
{
    constexpr int BK=32;
    __shared__ u16 AsH[128][BK+8];
    __shared__ u16 AsD[128][BK+8];
    __shared__ u16 BsH[64][BK+8];
    __shared__ u16 BsD[64][BK+8];
    const int tid = threadIdx.x;
    const int bm = blockIdx.x*128, bn = blockIdx.y*64;
    const int wave = tid>>6, lane = tid&63, lm = lane&15, lg = lane>>4;
    const int wm = (wave>>1)*64, wn = (wave&1)*32;
    f32x4 acc[4][2];
    #pragma unroll
    for(int i=0;i<4;i++){ acc[i][0]=(f32x4){0.f,0.f,0.f,0.f}; acc[i][1]=(f32x4){0.f,0.f,0.f,0.f}; }

    const int arow0 = tid>>2, akc0 = (tid&3)*8;
    const int arow1 = arow0 + 64;
    for(int k0=0;k0<256;k0+=BK){
        *(short8*)&AsH[arow0][akc0] = ld8b(Ah + (size_t)(bm+arow0)*256 + k0+akc0);
        *(short8*)&AsH[arow1][akc0] = ld8b(Ah + (size_t)(bm+arow1)*256 + k0+akc0);
        *(short8*)&AsD[arow0][akc0] = ld8b(Ad + (size_t)(bm+arow0)*256 + k0+akc0);
        *(short8*)&AsD[arow1][akc0] = ld8b(Ad + (size_t)(bm+arow1)*256 + k0+akc0);
        *(short8*)&BsH[arow0][akc0] = ld8f(w1 + (size_t)(bn+arow0)*256 + k0+akc0);
        *(short8*)&BsD[arow0][akc0] = ld8f(w2 + (size_t)(bn+arow0)*256 + k0+akc0);
        __syncthreads();
        short8 afH[4], afD[4], bf1[2], bf2[2];
        #pragma unroll
        for(int mt=0;mt<4;mt++){
            afH[mt] = *(const short8*)&AsH[wm+mt*16+lm][lg*8];
            afD[mt] = *(const short8*)&AsD[wm+mt*16+lm][lg*8];
        }
        #pragma unroll
        for(int nt=0;nt<2;nt++){
            bf1[nt] = *(const short8*)&BsH[wn+nt*16+lm][lg*8];
            bf2[nt] = *(const short8*)&BsD[wn+nt*16+lm][lg*8];
        }
        #pragma unroll
        for(int nt=0;nt<2;nt++)
            #pragma unroll
            for(int mt=0;mt<4;mt++){
                acc[mt][nt] = __builtin_amdgcn_mfma_f32_16x16x32_bf16(afH[mt], bf1[nt], acc[mt][nt], 0,0,0);
                acc[mt][nt] = __builtin_amdgcn_mfma_f32_16x16x32_bf16(afD[mt], bf2[nt], acc[mt][nt], 0,0,0);
            }
        __syncthreads();
    }
    #pragma unroll
    for(int nt=0;nt<2;nt++){
        const int col = bn+wn+nt*16+lm;
        const float bb = b1[col]+b2[col];
        #pragma unroll
        for(int mt=0;mt<4;mt++){
            const int row0 = bm+wm+mt*16+lg*4;
            #pragma unroll
            for(int r=0;r<4;r++){
                const float x = acc[mt][nt][r] + bb;
                theta[(size_t)(row0+r)*256 + col] = f2b(1.f/(1.f+__expf(-x)));
            }
        }
    }
}

// =============== final gather: one wave per (b,t), three outputs ===============
__global__ __launch_bounds__(256) void k_out(
    const int* __restrict__ skill,
    const u16* __restrict__ hall_hg, const u16* __restrict__ hall_dg,
    const u16* __restrict__ theta,
    const float* __restrict__ fc_h_w, const float* __restrict__ fc_h_b,
    const float* __restrict__ fc_d_w, const float* __restrict__ fc_d_b,
    const float* __restrict__ fc_e_w, const float* __restrict__ fc_e_b,
    float* __restrict__ outp)
{
    const int tid=threadIdx.x, lane=tid&63;
    const int wid = blockIdx.x*4 + (tid>>6);        // 0..31935
    const int b = wid/499, t = wid - b*499;
    const int ns = skill[b*500 + t + 1];
    float o0=0.f,o1=0.f,o2=0.f,bh=0.f,bd=0.f,be=0.f;
    if(ns != 100){
        const int c = iclamp(ns, 0, 99);
        const size_t r = (size_t)t*64 + b;
        const int k = lane*4;
        short4v hh  = *(const short4v*)&hall_hg[r*256+k];
        short4v hd  = *(const short4v*)&hall_dg[r*256+k];
        short4v th  = *(const short4v*)&theta[r*256+k];
        f32x4 fh  = *(const f32x4*)&fc_h_w[(size_t)c*256+k];
        f32x4 fd  = *(const f32x4*)&fc_d_w[(size_t)c*256+k];
        f32x4 fe1 = *(const f32x4*)&fc_e_w[(size_t)c*512+k];
        f32x4 fe2 = *(const f32x4*)&fc_e_w[(size_t)c*512+256+k];
        #pragma unroll
        for(int j=0;j<4;j++){
            const float hhj=b2f((u16)hh[j]), hdj=b2f((u16)hd[j]), tj=b2f((u16)th[j]);
            o0 += hhj*fh[j];
            o1 += hdj*fd[j];
            o2 += tj*hhj*fe1[j] + (1.f-tj)*hdj*fe2[j];
        }
        #pragma unroll
        for(int off=32;off>0;off>>=1){
            o0 += __shfl_down(o0,off);
            o1 += __shfl_down(o1,off);
            o2 += __shfl_down(o2,off);
        }
        bh=fc_h_b[c]; bd=fc_d_b[c]; be=fc_e_b[c];
    }
    if(lane==0){
        outp[            b*499+t] = (ns==100)?0.f:(o0+bh);
        outp[31936     + b*499+t] = (ns==100)?0.f:(o1+bd);
        outp[2*31936   + b*499+t] = (ns==100)?0.f:(o2+be);
    }
}

// ================================= launch =================================
extern "C" void kernel_launch(void* const* d_in, const int* in_sizes, int n_in,
                              void* d_out, int out_size, void* d_ws, size_t ws_size,
                              hipStream_t stream)
{
    const int* student = (const int*)d_in[0];
    const int* skill   = (const int*)d_in[1];
    const int* answer  = (const int*)d_in[2];
    const float* G        = (const float*)d_in[3];
    const float* skill_emb= (const float*)d_in[4];
    const float* answer_emb=(const float*)d_in[5];
    const float* stu      = (const float*)d_in[6];
    const float* hg_w1    = (const float*)d_in[7];
    const float* hg_b1    = (const float*)d_in[8];
    const float* hg_w2    = (const float*)d_in[9];
    const float* hg_b2    = (const float*)d_in[10];
    const float* gcn_w1   = (const float*)d_in[11];
    const float* gcn_b1   = (const float*)d_in[12];
    const float* gcn_w2   = (const float*)d_in[13];
    const float* gcn_b2   = (const float*)d_in[14];
    const float* w1_w     = (const float*)d_in[15];
    const float* w1_b     = (const float*)d_in[16];
    const float* w2_w     = (const float*)d_in[17];
    const float* w2_b     = (const float*)d_in[18];
    const float* fc_d_w   = (const float*)d_in[19];
    const float* fc_d_b   = (const float*)d_in[20];
    const float* fc_h_w   = (const float*)d_in[21];
    const float* fc_h_b   = (const float*)d_in[22];
    const float* fc_e_w   = (const float*)d_in[23];
    const float* fc_e_b   = (const float*)d_in[24];
    const float* pos      = (const float*)d_in[25];
    const float* dg_wih   = (const float*)d_in[26];
    const float* dg_whh   = (const float*)d_in[27];
    const float* dg_bih   = (const float*)d_in[28];
    const float* dg_bhh   = (const float*)d_in[29];
    const float* hgr_wih  = (const float*)d_in[30];
    const float* hgr_whh  = (const float*)d_in[31];
    const float* hgr_bih  = (const float*)d_in[32];
    const float* hgr_bhh  = (const float*)d_in[33];

    char* ws = (char*)d_ws;
    size_t off = 0;
    auto nxt = [&](size_t bytes)->char*{
        char* r = ws + off;
        off += (bytes + 255) & ~(size_t)255;
        return r;
    };
    float* h1pre      = (float*)nxt(808*4);
    float* pooled     = (float*)nxt(64*256*4);
    float* table_dg   = (float*)nxt(303*256*4);
    float* table_hg   = (float*)nxt(303*256*4);
    u16*   tmpT       = (u16*)  nxt((size_t)256*4096*2);
    u16*   hbuf       = (u16*)  nxt((size_t)4096*256*2);
    u16*   stu_proj   = (u16*)  nxt((size_t)4096*256*2);
    u16*   pooled_proj= (u16*)  nxt(64*256*2);
    int*   combo_t    = (int*)  nxt(32000*4);
    int*   sid_t      = (int*)  nxt(32000*4);
    u16*   hall_dg    = (u16*)  nxt((size_t)32000*256*2);   // 16.4 MB
    u16*   hall_hg    = (u16*)  nxt((size_t)32000*256*2);   // 16.4 MB
    u16*   theta      = (u16*)  nxt((size_t)32000*256*2);   // 16.4 MB

    // small prep
    k_h1pre<<<1,256,0,stream>>>(skill_emb, gcn_w1, h1pre);
    k_gcn<<<64,256,0,stream>>>(skill, answer, pos, h1pre, gcn_b1, gcn_w2, gcn_b2, pooled);
    k_table<<<303,256,0,stream>>>(skill_emb, answer_emb, dg_wih,  dg_bih,  dg_bhh,  table_dg);
    k_table<<<303,256,0,stream>>>(skill_emb, answer_emb, hgr_wih, hgr_bih, hgr_bhh, table_hg);
    k_idx<<<125,256,0,stream>>>(skill, answer, student, combo_t, sid_t);

    // student GCN chain over dense G
    gemm_bt<true ,false,true ,true ><<<dim3(32,4),256,0,stream>>>(stu,  hg_w1, hg_b1, tmpT, 4096,256,256,  256, 4096);
    gemm_bt<false,true ,true ,false><<<dim3(32,4),256,0,stream>>>(G,    tmpT,  nullptr, hbuf, 4096,256,4096, 4096, 256);
    gemm_bt<true ,false,false,true ><<<dim3(32,4),256,0,stream>>>(hbuf, hg_w2, hg_b2, tmpT, 4096,256,256,  256, 4096);
    gemm_bt<false,false,true ,false><<<dim3(32,4),256,0,stream>>>(G,    tmpT,  nullptr, hbuf, 4096,256,4096, 4096, 256);
    gemm_bt<false,false,false,true ><<<dim3(32,4),256,0,stream>>>(hbuf, hgr_wih, nullptr, stu_proj, 4096,256,256, 768, 256);

    k_pooledproj<<<64,256,0,stream>>>(pooled, dg_wih, pooled_proj);

    // recurrences: 8 blocks, register-resident Whh, pipelined gathers
    k_rnn<<<8,512,0,stream>>>(combo_t, sid_t, pooled_proj, stu_proj,
                              table_dg, table_hg, dg_whh, hgr_whh, hall_dg, hall_hg);

    // theta + outputs
    k_theta<<<dim3(250,4),256,0,stream>>>(hall_hg, hall_dg, w1_w, w2_w, w1_b, w2_b, theta);
    k_out<<<7984,256,0,stream>>>(skill, hall_hg, hall_dg, theta,
                                 fc_h_w, fc_h_b, fc_d_w, fc_d_b, fc_e_w, fc_e_b,
                                 (float*)d_out);
}

// Round 6
// 1123.304 us; speedup vs baseline: 5.8332x; 1.5605x over previous
//
#include <hip/hip_runtime.h>
#include <cstdint>
#include <cstddef>

typedef unsigned short u16;
typedef __attribute__((ext_vector_type(8))) short short8;
typedef __attribute__((ext_vector_type(4))) short short4v;
typedef __attribute__((ext_vector_type(4))) float f32x4;

__device__ __forceinline__ float b2f(u16 u){ return __uint_as_float(((unsigned)u)<<16); }
__device__ __forceinline__ u16 f2b(float f){
    unsigned u = __float_as_uint(f);
    return (u16)((u + 0x7fffu + ((u>>16)&1u)) >> 16);
}
__device__ __forceinline__ int iclamp(int v, int lo, int hi){ return v<lo?lo:(v>hi?hi:v); }

// 8-wide f32 -> bf16 fragment
__device__ __forceinline__ short8 ld8f(const float* p){
    f32x4 a = *(const f32x4*)p;
    f32x4 b = *(const f32x4*)(p+4);
    short8 r;
    #pragma unroll
    for(int j=0;j<4;j++){ r[j]=(short)f2b(a[j]); r[4+j]=(short)f2b(b[j]); }
    return r;
}
__device__ __forceinline__ short8 ld8b(const u16* p){ return *(const short8*)p; }

// =============== generic BT GEMM: C(MxN) = A(MxK) @ B(NxK)^T (+bias f32), bf16 out ===
// grid (M/128, N/64), block 256.
template<bool TRANSOUT, bool RELU, bool AF32, bool BF32>
__global__ __launch_bounds__(256) void gemm_bt(
    const void* __restrict__ A, const void* __restrict__ B,
    const float* __restrict__ bias, u16* __restrict__ C,
    int M, int N, int K, int ldb, int ldc)
{
    constexpr int BM=128, BN=64, BK=32;
    __shared__ u16 As[BM][BK+8];
    __shared__ u16 Bs[BN][BK+8];
    const int tid = threadIdx.x;
    const int bm = blockIdx.x*BM, bn = blockIdx.y*BN;
    const int wave = tid>>6, lane = tid&63, lm = lane&15, lg = lane>>4;
    const int wm = (wave>>1)*64, wn = (wave&1)*32;
    f32x4 acc[4][2];
    #pragma unroll
    for(int i=0;i<4;i++){ acc[i][0]=(f32x4){0.f,0.f,0.f,0.f}; acc[i][1]=(f32x4){0.f,0.f,0.f,0.f}; }

    const int arow0 = tid>>2, akc0 = (tid&3)*8;  // rows 0..63
    const int arow1 = arow0 + 64;                 // rows 64..127
    for(int k0=0;k0<K;k0+=BK){
        *(short8*)&As[arow0][akc0] = AF32 ? ld8f((const float*)A + (size_t)(bm+arow0)*K + k0+akc0)
                                          : ld8b((const u16*)A + (size_t)(bm+arow0)*K + k0+akc0);
        *(short8*)&As[arow1][akc0] = AF32 ? ld8f((const float*)A + (size_t)(bm+arow1)*K + k0+akc0)
                                          : ld8b((const u16*)A + (size_t)(bm+arow1)*K + k0+akc0);
        *(short8*)&Bs[arow0][akc0] = BF32 ? ld8f((const float*)B + (size_t)(bn+arow0)*ldb + k0+akc0)
                                          : ld8b((const u16*)B + (size_t)(bn+arow0)*ldb + k0+akc0);
        __syncthreads();
        short8 af[4], bfg[2];
        #pragma unroll
        for(int mt=0;mt<4;mt++) af[mt]  = *(const short8*)&As[wm+mt*16+lm][lg*8];
        #pragma unroll
        for(int nt=0;nt<2;nt++) bfg[nt] = *(const short8*)&Bs[wn+nt*16+lm][lg*8];
        #pragma unroll
        for(int nt=0;nt<2;nt++)
            #pragma unroll
            for(int mt=0;mt<4;mt++)
                acc[mt][nt] = __builtin_amdgcn_mfma_f32_16x16x32_bf16(af[mt], bfg[nt], acc[mt][nt], 0,0,0);
        __syncthreads();
    }
    #pragma unroll
    for(int nt=0;nt<2;nt++){
        const int col = bn+wn+nt*16+lm;
        const float bv = bias ? bias[col] : 0.f;
        #pragma unroll
        for(int mt=0;mt<4;mt++){
            const int row0 = bm+wm+mt*16+lg*4;
            #pragma unroll
            for(int r=0;r<4;r++){
                const int row = row0+r;
                float v = acc[mt][nt][r] + bv;
                if(RELU) v = fmaxf(v, 0.f);
                const size_t idx = TRANSOUT ? ((size_t)col*ldc + row) : ((size_t)row*ldc + col);
                C[idx] = f2b(v);
            }
        }
    }
}

// =============== h1_pre = skill_emb @ gcn_w1^T   (101x8, f32 in/out) ===============
__global__ __launch_bounds__(256) void k_h1pre(const float* __restrict__ skill_emb,
                                               const float* __restrict__ gcn_w1,
                                               float* __restrict__ h1pre)
{
    for(int i=threadIdx.x;i<808;i+=256){
        const int n=i>>3, j=i&7;
        float acc=0.f;
        for(int k=0;k<256;k++) acc += skill_emb[n*256+k]*gcn_w1[j*256+k];
        h1pre[i]=acc;
    }
}

// =============== combo/sid index arrays, t-major [t*64+b], clamped ===============
__global__ __launch_bounds__(256) void k_idx(const int* __restrict__ skill,
                                             const int* __restrict__ answer,
                                             const int* __restrict__ student,
                                             int* __restrict__ combo_t, int* __restrict__ sid_t)
{
    const int i = blockIdx.x*256 + threadIdx.x;
    if(i>=32000) return;
    const int t = i>>6, b = i&63;
    const int sk = iclamp(skill[b*500+t], 0, 100);
    const int an = iclamp(answer[b*500+t], 0, 2);
    const int sd = iclamp(student[b*500+t]-1, 0, 4095);
    combo_t[i] = sk*3+an;
    sid_t[i]   = sd;
}

// =============== per-batch skill GCN, softmax pooling -> pooled (64x256 f32) ===============
__global__ __launch_bounds__(256) void k_gcn(
    const int* __restrict__ skill, const int* __restrict__ answer,
    const float* __restrict__ pos, const float* __restrict__ h1pre,
    const float* __restrict__ gcn_b1, const float* __restrict__ gcn_w2, const float* __restrict__ gcn_b2,
    float* __restrict__ pooled)
{
    const int b = blockIdx.x, tid = threadIdx.x;
    __shared__ int   sk[500];
    __shared__ float msk[500];
    __shared__ float coef[500];
    __shared__ float deg[101];
    __shared__ float agg1[101*8];
    __shared__ float agg2[101*8];
    __shared__ float red[256];
    __shared__ float vec8[8];
    __shared__ float sS[1];

    for(int i=tid;i<500;i+=256){
        sk[i]=iclamp(skill[b*500+i],0,100);
        msk[i] = (answer[b*500+i]!=2)?1.f:0.f;
    }
    for(int i=tid;i<101;i+=256) deg[i]=1.f;           // self loop
    if(tid<8)  vec8[tid]=0.f;
    if(tid==8) sS[0]=0.f;
    __syncthreads();
    for(int e=tid;e<499;e+=256) atomicAdd(&deg[sk[e+1]], 1.f);
    __syncthreads();
    for(int i=tid;i<101;i+=256) deg[i] = rsqrtf(deg[i]);   // deg -> dinv
    float cnt=0.f; for(int i=tid;i<500;i+=256) cnt += msk[i];
    __syncthreads();
    red[tid]=cnt; __syncthreads();
    for(int s=128;s>0;s>>=1){ if(tid<s) red[tid]+=red[tid+s]; __syncthreads(); }
    const int len = iclamp((int)(red[0]+0.5f), 1, 500);
    __syncthreads();
    for(int i=tid;i<808;i+=256){ const int n=i>>3; agg1[i] = deg[n]*deg[n]*h1pre[i]; }
    __syncthreads();
    for(int i=tid;i<499*8;i+=256){
        const int e=i>>3, j=i&7, s=sk[e], d=sk[e+1];
        atomicAdd(&agg1[d*8+j], deg[s]*deg[d]*h1pre[s*8+j]);
    }
    __syncthreads();
    for(int i=tid;i<808;i+=256){ const int j=i&7; agg1[i] = fmaxf(agg1[i]+gcn_b1[j], 0.f); }
    __syncthreads();
    for(int i=tid;i<808;i+=256){ const int n=i>>3; agg2[i] = deg[n]*deg[n]*agg1[i]; }
    __syncthreads();
    for(int i=tid;i<499*8;i+=256){
        const int e=i>>3, j=i&7, s=sk[e], d=sk[e+1];
        atomicAdd(&agg2[d*8+j], deg[s]*deg[d]*agg1[s*8+j]);
    }
    const size_t prow = (size_t)(len-1)*500;
    float vmax = -1e30f;
    for(int i=tid;i<500;i+=256){ const float v = pos[prow+i]*msk[i]; coef[i]=v; vmax=fmaxf(vmax,v); }
    red[tid]=vmax; __syncthreads();           // also orders agg2 atomics
    for(int s=128;s>0;s>>=1){ if(tid<s) red[tid]=fmaxf(red[tid],red[tid+s]); __syncthreads(); }
    const float m = red[0]; __syncthreads();
    float lsum=0.f;
    for(int i=tid;i<500;i+=256){ const float e=__expf(coef[i]-m); coef[i]=e; lsum+=e; }
    red[tid]=lsum; __syncthreads();
    for(int s=128;s>0;s>>=1){ if(tid<s) red[tid]+=red[tid+s]; __syncthreads(); }
    const float inv = 1.f/red[0];
    __syncthreads();
    float v8[8]={0,0,0,0,0,0,0,0}; float ls=0.f;
    for(int i=tid;i<500;i+=256){
        const float ci = coef[i]*inv*msk[i];
        if(ci!=0.f){
            const int n=sk[i]; ls+=ci;
            #pragma unroll
            for(int j=0;j<8;j++) v8[j] += ci*agg2[n*8+j];
        }
    }
    #pragma unroll
    for(int j=0;j<8;j++) atomicAdd(&vec8[j], v8[j]);
    atomicAdd(&sS[0], ls);
    __syncthreads();
    {
        const int o = tid;
        float acc = gcn_b2[o]*sS[0];
        #pragma unroll
        for(int j=0;j<8;j++) acc += vec8[j]*gcn_w2[o*8+j];
        pooled[b*256+o] = acc;
    }
}

// ====== x-part tables: table[combo] = x(skill,answer) @ Wih[:,256:768]^T + bih + bhh ======
__global__ __launch_bounds__(256) void k_table(
    const float* __restrict__ skill_emb, const float* __restrict__ answer_emb,
    const float* __restrict__ wih, const float* __restrict__ bih, const float* __restrict__ bhh,
    float* __restrict__ table)
{
    const int combo = blockIdx.x, tid = threadIdx.x;
    const int sid = combo/3, ans = combo - sid*3;
    __shared__ float sf[256], sg[256];
    sf[tid] = (ans==1) ? skill_emb[(size_t)sid*256+tid] : answer_emb[(size_t)ans*256+tid];
    sg[tid] = (ans==1) ? answer_emb[(size_t)ans*256+tid] : skill_emb[(size_t)sid*256+tid];
    __syncthreads();
    const int o = tid;
    float acc = bih[o] + bhh[o];
    const float* w = wih + (size_t)o*768;
    for(int k=0;k<256;k++) acc += sf[k]*w[256+k] + sg[k]*w[512+k];
    table[(size_t)combo*256 + o] = acc;
}

// =============== pooled_proj[b] = pooled[b] @ dg_wih[:, :256]^T  (bf16 64x256) ===============
__global__ __launch_bounds__(256) void k_pooledproj(const float* __restrict__ pooled,
                                                    const float* __restrict__ wih,
                                                    u16* __restrict__ outp)
{
    const int b=blockIdx.x, tid=threadIdx.x;
    __shared__ float p[256];
    p[tid] = pooled[b*256+tid];
    __syncthreads();
    const float* w = wih + (size_t)tid*768;
    float acc=0.f;
    for(int k=0;k<256;k++) acc += p[k]*w[k];
    outp[b*256+tid]=f2b(acc);
}

// ====== k_pre: pre[rnn][t][b][c] = table[combo] + proj  (bf16, t-major) ======
// grid (500, 2), block 256.
__global__ __launch_bounds__(256) void k_pre(
    const int* __restrict__ combo_t, const int* __restrict__ sid_t,
    const float* __restrict__ table_dg, const float* __restrict__ table_hg,
    const u16* __restrict__ pooled_proj, const u16* __restrict__ stu_proj,
    u16* __restrict__ pre_dg, u16* __restrict__ pre_hg)
{
    const int t = blockIdx.x, rnn = blockIdx.y, c = threadIdx.x;
    const float* tab = rnn ? table_hg : table_dg;
    u16* outp = rnn ? pre_hg : pre_dg;
    for(int b=0;b<64;b++){
        const int cmb = combo_t[t*64+b];
        const u16* prow = rnn ? (stu_proj + (size_t)sid_t[t*64+b]*256)
                              : (pooled_proj + (size_t)b*256);
        const float v = tab[(size_t)cmb*256 + c] + b2f(prow[c]);
        outp[((size_t)t*64+b)*256 + c] = f2b(v);
    }
}

// =============== RNN v3: transposed MFMA (W = A-operand), conflict-free LDS ======
// 8 blocks = (rnn, 16-row group), 8 waves; wave owns output cols [wave*32, +32).
// h stored in LDS as A/B-fragment chunks: hc[buf][kk][lg][lm][8] (16B per lane, conflict-free).
__global__ __launch_bounds__(512) void k_rnn(
    const u16* __restrict__ pre_dg, const u16* __restrict__ pre_hg,
    const float* __restrict__ whh_dg, const float* __restrict__ whh_hg,
    u16* __restrict__ hall_dg, u16* __restrict__ hall_hg)
{
    __shared__ u16 hc[2][8][4][16][8];    // 2 x 8KB
    const int bid = blockIdx.x;
    const int rnn = bid>>2, grp = bid&3, rb = grp*16;
    const float* W   = rnn ? whh_hg : whh_dg;
    const u16*  pre  = rnn ? pre_hg : pre_dg;
    u16*        out  = rnn ? hall_hg : hall_dg;
    const int tid = threadIdx.x, wave = tid>>6, lane = tid&63;
    const int lm = lane&15, lg = lane>>4;
    const int cb = wave*32;

    // W fragments as A-operand: A[m = W row = out col][k], resident in registers
    short8 wf[2][8];
    #pragma unroll
    for(int nt=0;nt<2;nt++)
        #pragma unroll
        for(int kk=0;kk<8;kk++)
            wf[nt][kk] = ld8f(W + (size_t)(cb+nt*16+lm)*256 + kk*32 + lg*8);

    for(int i=tid;i<2*8*4*16*8;i+=512) ((u16*)hc)[i]=0;

    const size_t rowoff = (size_t)(rb+lm)*256;
    // prefetch t=0 pre (4 consecutive bf16 per tile)
    uint2 pv[2];
    #pragma unroll
    for(int nt=0;nt<2;nt++)
        pv[nt] = *(const uint2*)&pre[rowoff + cb + nt*16 + lg*4];
    __syncthreads();

    int cur = 0;
    for(int t=0;t<500;t++){
        // D = W @ h^T : B-frag = h[row=lm][k] from chunk layout (conflict-free)
        f32x4 acc0 = {0.f,0.f,0.f,0.f}, acc1 = {0.f,0.f,0.f,0.f};
        #pragma unroll
        for(int kk=0;kk<8;kk++){
            short8 hb = *(const short8*)&hc[cur][kk][lg][lm][0];
            acc0 = __builtin_amdgcn_mfma_f32_16x16x32_bf16(wf[0][kk], hb, acc0, 0,0,0);
            acc1 = __builtin_amdgcn_mfma_f32_16x16x32_bf16(wf[1][kk], hb, acc1, 0,0,0);
        }
        // prefetch next step's pre
        uint2 pvn[2];
        {
            const int tn = (t<499)? t+1 : 499;
            const size_t base = (size_t)tn*64*256 + rowoff;
            pvn[0] = *(const uint2*)&pre[base + cb + lg*4];
            pvn[1] = *(const uint2*)&pre[base + cb + 16 + lg*4];
        }
        // epilogue: lane holds rows=lm, cols cb+nt*16+lg*4..+3 (4 consecutive cols)
        #pragma unroll
        for(int nt=0;nt<2;nt++){
            const f32x4 a = nt ? acc1 : acc0;
            const unsigned plo = pv[nt].x, phi = pv[nt].y;
            u16 hv[4];
            #pragma unroll
            for(int r=0;r<4;r++){
                const u16 pb = (u16)(((r<2)? plo : phi) >> ((r&1)*16));
                const float v = a[r] + b2f(pb);
                const float e = __expf(2.f*v);
                hv[r] = f2b(1.f - 2.f/(e+1.f));    // tanh
            }
            uint2 pk;
            pk.x = (unsigned)hv[0] | ((unsigned)hv[1]<<16);
            pk.y = (unsigned)hv[2] | ((unsigned)hv[3]<<16);
            // LDS chunk dest: kk'=wave, lg' = nt*2+(lg>>1), j0 = (lg&1)*4
            *(uint2*)&hc[cur^1][wave][nt*2+(lg>>1)][lm][(lg&1)*4] = pk;
            // global hall store (8B, row-major)
            *(uint2*)&out[(size_t)t*64*256 + rowoff + cb + nt*16 + lg*4] = pk;
        }
        __syncthreads();
        pv[0]=pvn[0]; pv[1]=pvn[1];
        cur ^= 1;
    }
}

// ====== theta = sigmoid(h_hg@w1^T + h_dg@w2^T + b1 + b2), dual-GEMM fused, bf16 out ======
// grid (250, 4), block 256.  M=32000, N=256, K=256.
__global__ __launch_bounds__(256) void k_theta(
    const u16* __restrict__ Ah, const u16* __restrict__ Ad,
    const float* __restrict__ w1, const float* __restrict__ w2,
    const float* __restrict__ b1, const float* __restrict__ b2,
    u16* __restrict__ theta)
{
    constexpr int BK=32;
    __shared__ u16 AsH[128][BK+8];
    __shared__ u16 AsD[128][BK+8];
    __shared__ u16 BsH[64][BK+8];
    __shared__ u16 BsD[64][BK+8];
    const int tid = threadIdx.x;
    const int bm = blockIdx.x*128, bn = blockIdx.y*64;
    const int wave = tid>>6, lane = tid&63, lm = lane&15, lg = lane>>4;
    const int wm = (wave>>1)*64, wn = (wave&1)*32;
    f32x4 acc[4][2];
    #pragma unroll
    for(int i=0;i<4;i++){ acc[i][0]=(f32x4){0.f,0.f,0.f,0.f}; acc[i][1]=(f32x4){0.f,0.f,0.f,0.f}; }

    const int arow0 = tid>>2, akc0 = (tid&3)*8;
    const int arow1 = arow0 + 64;
    for(int k0=0;k0<256;k0+=BK){
        *(short8*)&AsH[arow0][akc0] = ld8b(Ah + (size_t)(bm+arow0)*256 + k0+akc0);
        *(short8*)&AsH[arow1][akc0] = ld8b(Ah + (size_t)(bm+arow1)*256 + k0+akc0);
        *(short8*)&AsD[arow0][akc0] = ld8b(Ad + (size_t)(bm+arow0)*256 + k0+akc0);
        *(short8*)&AsD[arow1][akc0] = ld8b(Ad + (size_t)(bm+arow1)*256 + k0+akc0);
        *(short8*)&BsH[arow0][akc0] = ld8f(w1 + (size_t)(bn+arow0)*256 + k0+akc0);
        *(short8*)&BsD[arow0][akc0] = ld8f(w2 + (size_t)(bn+arow0)*256 + k0+akc0);
        __syncthreads();
        short8 afH[4], afD[4], bf1[2], bf2[2];
        #pragma unroll
        for(int mt=0;mt<4;mt++){
            afH[mt] = *(const short8*)&AsH[wm+mt*16+lm][lg*8];
            afD[mt] = *(const short8*)&AsD[wm+mt*16+lm][lg*8];
        }
        #pragma unroll
        for(int nt=0;nt<2;nt++){
            bf1[nt] = *(const short8*)&BsH[wn+nt*16+lm][lg*8];
            bf2[nt] = *(const short8*)&BsD[wn+nt*16+lm][lg*8];
        }
        #pragma unroll
        for(int nt=0;nt<2;nt++)
            #pragma unroll
            for(int mt=0;mt<4;mt++){
                acc[mt][nt] = __builtin_amdgcn_mfma_f32_16x16x32_bf16(afH[mt], bf1[nt], acc[mt][nt], 0,0,0);
                acc[mt][nt] = __builtin_amdgcn_mfma_f32_16x16x32_bf16(afD[mt], bf2[nt], acc[mt][nt], 0,0,0);
            }
        __syncthreads();
    }
    #pragma unroll
    for(int nt=0;nt<2;nt++){
        const int col = bn+wn+nt*16+lm;
        const float bb = b1[col]+b2[col];
        #pragma unroll
        for(int mt=0;mt<4;mt++){
            const int row0 = bm+wm+mt*16+lg*4;
            #pragma unroll
            for(int r=0;r<4;r++){
                const float x = acc[mt][nt][r] + bb;
                theta[(size_t)(row0+r)*256 + col] = f2b(1.f/(1.f+__expf(-x)));
            }
        }
    }
}

// =============== final gather: one wave per (b,t), three outputs ===============
__global__ __launch_bounds__(256) void k_out(
    const int* __restrict__ skill,
    const u16* __restrict__ hall_hg, const u16* __restrict__ hall_dg,
    const u16* __restrict__ theta,
    const float* __restrict__ fc_h_w, const float* __restrict__ fc_h_b,
    const float* __restrict__ fc_d_w, const float* __restrict__ fc_d_b,
    const float* __restrict__ fc_e_w, const float* __restrict__ fc_e_b,
    float* __restrict__ outp)
{
    const int tid=threadIdx.x, lane=tid&63;
    const int wid = blockIdx.x*4 + (tid>>6);        // 0..31935
    const int b = wid/499, t = wid - b*499;
    const int ns = skill[b*500 + t + 1];
    float o0=0.f,o1=0.f,o2=0.f,bh=0.f,bd=0.f,be=0.f;
    if(ns != 100){
        const int c = iclamp(ns, 0, 99);
        const size_t r = (size_t)t*64 + b;
        const int k = lane*4;
        short4v hh  = *(const short4v*)&hall_hg[r*256+k];
        short4v hd  = *(const short4v*)&hall_dg[r*256+k];
        short4v th  = *(const short4v*)&theta[r*256+k];
        f32x4 fh  = *(const f32x4*)&fc_h_w[(size_t)c*256+k];
        f32x4 fd  = *(const f32x4*)&fc_d_w[(size_t)c*256+k];
        f32x4 fe1 = *(const f32x4*)&fc_e_w[(size_t)c*512+k];
        f32x4 fe2 = *(const f32x4*)&fc_e_w[(size_t)c*512+256+k];
        #pragma unroll
        for(int j=0;j<4;j++){
            const float hhj=b2f((u16)hh[j]), hdj=b2f((u16)hd[j]), tj=b2f((u16)th[j]);
            o0 += hhj*fh[j];
            o1 += hdj*fd[j];
            o2 += tj*hhj*fe1[j] + (1.f-tj)*hdj*fe2[j];
        }
        #pragma unroll
        for(int off=32;off>0;off>>=1){
            o0 += __shfl_down(o0,off);
            o1 += __shfl_down(o1,off);
            o2 += __shfl_down(o2,off);
        }
        bh=fc_h_b[c]; bd=fc_d_b[c]; be=fc_e_b[c];
    }
    if(lane==0){
        outp[            b*499+t] = (ns==100)?0.f:(o0+bh);
        outp[31936     + b*499+t] = (ns==100)?0.f:(o1+bd);
        outp[2*31936   + b*499+t] = (ns==100)?0.f:(o2+be);
    }
}

// ================================= launch =================================
extern "C" void kernel_launch(void* const* d_in, const int* in_sizes, int n_in,
                              void* d_out, int out_size, void* d_ws, size_t ws_size,
                              hipStream_t stream)
{
    const int* student = (const int*)d_in[0];
    const int* skill   = (const int*)d_in[1];
    const int* answer  = (const int*)d_in[2];
    const float* G        = (const float*)d_in[3];
    const float* skill_emb= (const float*)d_in[4];
    const float* answer_emb=(const float*)d_in[5];
    const float* stu      = (const float*)d_in[6];
    const float* hg_w1    = (const float*)d_in[7];
    const float* hg_b1    = (const float*)d_in[8];
    const float* hg_w2    = (const float*)d_in[9];
    const float* hg_b2    = (const float*)d_in[10];
    const float* gcn_w1   = (const float*)d_in[11];
    const float* gcn_b1   = (const float*)d_in[12];
    const float* gcn_w2   = (const float*)d_in[13];
    const float* gcn_b2   = (const float*)d_in[14];
    const float* w1_w     = (const float*)d_in[15];
    const float* w1_b     = (const float*)d_in[16];
    const float* w2_w     = (const float*)d_in[17];
    const float* w2_b     = (const float*)d_in[18];
    const float* fc_d_w   = (const float*)d_in[19];
    const float* fc_d_b   = (const float*)d_in[20];
    const float* fc_h_w   = (const float*)d_in[21];
    const float* fc_h_b   = (const float*)d_in[22];
    const float* fc_e_w   = (const float*)d_in[23];
    const float* fc_e_b   = (const float*)d_in[24];
    const float* pos      = (const float*)d_in[25];
    const float* dg_wih   = (const float*)d_in[26];
    const float* dg_whh   = (const float*)d_in[27];
    const float* dg_bih   = (const float*)d_in[28];
    const float* dg_bhh   = (const float*)d_in[29];
    const float* hgr_wih  = (const float*)d_in[30];
    const float* hgr_whh  = (const float*)d_in[31];
    const float* hgr_bih  = (const float*)d_in[32];
    const float* hgr_bhh  = (const float*)d_in[33];

    char* ws = (char*)d_ws;
    size_t off = 0;
    auto nxt = [&](size_t bytes)->char*{
        char* r = ws + off;
        off += (bytes + 255) & ~(size_t)255;
        return r;
    };
    float* h1pre      = (float*)nxt(808*4);
    float* pooled     = (float*)nxt(64*256*4);
    float* table_dg   = (float*)nxt(303*256*4);
    float* table_hg   = (float*)nxt(303*256*4);
    u16*   tmpT       = (u16*)  nxt((size_t)256*4096*2);
    u16*   hbuf       = (u16*)  nxt((size_t)4096*256*2);
    u16*   stu_proj   = (u16*)  nxt((size_t)4096*256*2);
    u16*   pooled_proj= (u16*)  nxt(64*256*2);
    int*   combo_t    = (int*)  nxt(32000*4);
    int*   sid_t      = (int*)  nxt(32000*4);
    u16*   hall_dg    = (u16*)  nxt((size_t)32000*256*2);   // 16.4 MB
    u16*   hall_hg    = (u16*)  nxt((size_t)32000*256*2);   // 16.4 MB
    u16*   pre_dg     = (u16*)  nxt((size_t)32000*256*2);   // 16.4 MB (reused as theta)
    u16*   pre_hg     = (u16*)  nxt((size_t)32000*256*2);   // 16.4 MB
    u16*   theta      = pre_dg;                              // pre_dg dead after k_rnn

    // small prep
    k_h1pre<<<1,256,0,stream>>>(skill_emb, gcn_w1, h1pre);
    k_gcn<<<64,256,0,stream>>>(skill, answer, pos, h1pre, gcn_b1, gcn_w2, gcn_b2, pooled);
    k_table<<<303,256,0,stream>>>(skill_emb, answer_emb, dg_wih,  dg_bih,  dg_bhh,  table_dg);
    k_table<<<303,256,0,stream>>>(skill_emb, answer_emb, hgr_wih, hgr_bih, hgr_bhh, table_hg);
    k_idx<<<125,256,0,stream>>>(skill, answer, student, combo_t, sid_t);

    // student GCN chain over dense G
    gemm_bt<true ,false,true ,true ><<<dim3(32,4),256,0,stream>>>(stu,  hg_w1, hg_b1, tmpT, 4096,256,256,  256, 4096);
    gemm_bt<false,true ,true ,false><<<dim3(32,4),256,0,stream>>>(G,    tmpT,  nullptr, hbuf, 4096,256,4096, 4096, 256);
    gemm_bt<true ,false,false,true ><<<dim3(32,4),256,0,stream>>>(hbuf, hg_w2, hg_b2, tmpT, 4096,256,256,  256, 4096);
    gemm_bt<false,false,true ,false><<<dim3(32,4),256,0,stream>>>(G,    tmpT,  nullptr, hbuf, 4096,256,4096, 4096, 256);
    gemm_bt<false,false,false,true ><<<dim3(32,4),256,0,stream>>>(hbuf, hgr_wih, nullptr, stu_proj, 4096,256,256, 768, 256);

    k_pooledproj<<<64,256,0,stream>>>(pooled, dg_wih, pooled_proj);

    // fused pre-activation array (t-major bf16)
    k_pre<<<dim3(500,2),256,0,stream>>>(combo_t, sid_t, table_dg, table_hg,
                                        pooled_proj, stu_proj, pre_dg, pre_hg);

    // recurrences: transposed MFMA, conflict-free LDS, wide packed stores
    k_rnn<<<8,512,0,stream>>>(pre_dg, pre_hg, dg_whh, hgr_whh, hall_dg, hall_hg);

    // theta + outputs
    k_theta<<<dim3(250,4),256,0,stream>>>(hall_hg, hall_dg, w1_w, w2_w, w1_b, w2_b, theta);
    k_out<<<7984,256,0,stream>>>(skill, hall_hg, hall_dg, theta,
                                 fc_h_w, fc_h_b, fc_d_w, fc_d_b, fc_e_w, fc_e_b,
                                 (float*)d_out);
}

// Round 7
// 971.893 us; speedup vs baseline: 6.7420x; 1.1558x over previous
//
#include <hip/hip_runtime.h>
#include <cstdint>
#include <cstddef>

typedef unsigned short u16;
typedef __attribute__((ext_vector_type(8))) short short8;
typedef __attribute__((ext_vector_type(4))) short short4v;
typedef __attribute__((ext_vector_type(4))) float f32x4;

__device__ __forceinline__ float b2f(u16 u){ return __uint_as_float(((unsigned)u)<<16); }
__device__ __forceinline__ u16 f2b(float f){
    unsigned u = __float_as_uint(f);
    return (u16)((u + 0x7fffu + ((u>>16)&1u)) >> 16);
}
__device__ __forceinline__ u16 f2b_fast(float f){          // round-half-up (2 ops)
    return (u16)((__float_as_uint(f) + 0x8000u) >> 16);
}
__device__ __forceinline__ int iclamp(int v, int lo, int hi){ return v<lo?lo:(v>hi?hi:v); }

// LDS-only barrier: no vmcnt(0) drain (global loads/stores stay in flight)
__device__ __forceinline__ void barrier_lds(){
    asm volatile("s_waitcnt lgkmcnt(0)\n\ts_barrier" ::: "memory");
}

// 8-wide f32 -> bf16 fragment
__device__ __forceinline__ short8 ld8f(const float* p){
    f32x4 a = *(const f32x4*)p;
    f32x4 b = *(const f32x4*)(p+4);
    short8 r;
    #pragma unroll
    for(int j=0;j<4;j++){ r[j]=(short)f2b(a[j]); r[4+j]=(short)f2b(b[j]); }
    return r;
}
__device__ __forceinline__ short8 ld8b(const u16* p){ return *(const short8*)p; }

// =============== G f32 -> bf16 (4096x4096) ===============
__global__ __launch_bounds__(256) void k_cvt(const float* __restrict__ in, u16* __restrict__ outp){
    const size_t i = ((size_t)blockIdx.x*256 + threadIdx.x)*8;
    *(short8*)&outp[i] = ld8f(in + i);
}

// =============== 64x64-tile BT GEMM: C(MxN) = A(MxK) @ B(NxK)^T (+bias f32), bf16 out ===
// grid (M/64, N/64), block 256 (4 waves, each 32x32 output).
template<bool TRANSOUT, bool RELU, bool AF32, bool BF32>
__global__ __launch_bounds__(256) void gemm64(
    const void* __restrict__ A, const void* __restrict__ B,
    const float* __restrict__ bias, u16* __restrict__ C,
    int M, int N, int K, int ldb, int ldc)
{
    constexpr int BK=32;
    __shared__ u16 As[64][BK+8];
    __shared__ u16 Bs[64][BK+8];
    const int tid = threadIdx.x;
    const int bm = blockIdx.x*64, bn = blockIdx.y*64;
    const int wave = tid>>6, lane = tid&63, lm = lane&15, lg = lane>>4;
    const int wm = (wave>>1)*32, wn = (wave&1)*32;
    f32x4 acc[2][2];
    #pragma unroll
    for(int i=0;i<2;i++){ acc[i][0]=(f32x4){0.f,0.f,0.f,0.f}; acc[i][1]=(f32x4){0.f,0.f,0.f,0.f}; }

    const int arow = tid>>2, akc = (tid&3)*8;
    for(int k0=0;k0<K;k0+=BK){
        *(short8*)&As[arow][akc] = AF32 ? ld8f((const float*)A + (size_t)(bm+arow)*K + k0+akc)
                                        : ld8b((const u16*)A + (size_t)(bm+arow)*K + k0+akc);
        *(short8*)&Bs[arow][akc] = BF32 ? ld8f((const float*)B + (size_t)(bn+arow)*ldb + k0+akc)
                                        : ld8b((const u16*)B + (size_t)(bn+arow)*ldb + k0+akc);
        __syncthreads();
        short8 af[2], bfg[2];
        #pragma unroll
        for(int mt=0;mt<2;mt++) af[mt]  = *(const short8*)&As[wm+mt*16+lm][lg*8];
        #pragma unroll
        for(int nt=0;nt<2;nt++) bfg[nt] = *(const short8*)&Bs[wn+nt*16+lm][lg*8];
        #pragma unroll
        for(int nt=0;nt<2;nt++)
            #pragma unroll
            for(int mt=0;mt<2;mt++)
                acc[mt][nt] = __builtin_amdgcn_mfma_f32_16x16x32_bf16(af[mt], bfg[nt], acc[mt][nt], 0,0,0);
        __syncthreads();
    }
    #pragma unroll
    for(int nt=0;nt<2;nt++){
        const int col = bn+wn+nt*16+lm;
        const float bv = bias ? bias[col] : 0.f;
        #pragma unroll
        for(int mt=0;mt<2;mt++){
            const int row0 = bm+wm+mt*16+lg*4;
            #pragma unroll
            for(int r=0;r<4;r++){
                const int row = row0+r;
                float v = acc[mt][nt][r] + bv;
                if(RELU) v = fmaxf(v, 0.f);
                const size_t idx = TRANSOUT ? ((size_t)col*ldc + row) : ((size_t)row*ldc + col);
                C[idx] = f2b(v);
            }
        }
    }
}

// =============== h1_pre = skill_emb @ gcn_w1^T   (101x8, f32 in/out), 8 blocks ========
__global__ __launch_bounds__(256) void k_h1pre(const float* __restrict__ skill_emb,
                                               const float* __restrict__ gcn_w1,
                                               float* __restrict__ h1pre)
{
    const int i = blockIdx.x*101 + threadIdx.x;
    if(threadIdx.x >= 101) return;
    // i in [0,808): n=i>>3 j=i&7 ordering preserved by striding over all 808
    const int idx = i; if(idx>=808) return;
    const int n=idx>>3, j=idx&7;
    const float* x = skill_emb + n*256;
    const float* w = gcn_w1 + j*256;
    float acc=0.f;
    for(int k=0;k<256;k+=4){
        f32x4 a = *(const f32x4*)&x[k];
        f32x4 b = *(const f32x4*)&w[k];
        acc += a.x*b.x + a.y*b.y + a.z*b.z + a.w*b.w;
    }
    h1pre[idx]=acc;
}

// =============== combo/sid index arrays, t-major [t*64+b], clamped ===============
__global__ __launch_bounds__(256) void k_idx(const int* __restrict__ skill,
                                             const int* __restrict__ answer,
                                             const int* __restrict__ student,
                                             int* __restrict__ combo_t, int* __restrict__ sid_t)
{
    const int i = blockIdx.x*256 + threadIdx.x;
    if(i>=32000) return;
    const int t = i>>6, b = i&63;
    const int sk = iclamp(skill[b*500+t], 0, 100);
    const int an = iclamp(answer[b*500+t], 0, 2);
    const int sd = iclamp(student[b*500+t]-1, 0, 4095);
    combo_t[i] = sk*3+an;
    sid_t[i]   = sd;
}

// =============== per-batch skill GCN, softmax pooling -> pooled (64x256 f32) ===============
__global__ __launch_bounds__(256) void k_gcn(
    const int* __restrict__ skill, const int* __restrict__ answer,
    const float* __restrict__ pos, const float* __restrict__ h1pre,
    const float* __restrict__ gcn_b1, const float* __restrict__ gcn_w2, const float* __restrict__ gcn_b2,
    float* __restrict__ pooled)
{
    const int b = blockIdx.x, tid = threadIdx.x;
    __shared__ int   sk[500];
    __shared__ float msk[500];
    __shared__ float coef[500];
    __shared__ float deg[101];
    __shared__ float agg1[101*8];
    __shared__ float agg2[101*8];
    __shared__ float red[256];
    __shared__ float vec8[8];
    __shared__ float sS[1];

    for(int i=tid;i<500;i+=256){
        sk[i]=iclamp(skill[b*500+i],0,100);
        msk[i] = (answer[b*500+i]!=2)?1.f:0.f;
    }
    for(int i=tid;i<101;i+=256) deg[i]=1.f;           // self loop
    if(tid<8)  vec8[tid]=0.f;
    if(tid==8) sS[0]=0.f;
    __syncthreads();
    for(int e=tid;e<499;e+=256) atomicAdd(&deg[sk[e+1]], 1.f);
    __syncthreads();
    for(int i=tid;i<101;i+=256) deg[i] = rsqrtf(deg[i]);   // deg -> dinv
    float cnt=0.f; for(int i=tid;i<500;i+=256) cnt += msk[i];
    __syncthreads();
    red[tid]=cnt; __syncthreads();
    for(int s=128;s>0;s>>=1){ if(tid<s) red[tid]+=red[tid+s]; __syncthreads(); }
    const int len = iclamp((int)(red[0]+0.5f), 1, 500);
    __syncthreads();
    for(int i=tid;i<808;i+=256){ const int n=i>>3; agg1[i] = deg[n]*deg[n]*h1pre[i]; }
    __syncthreads();
    for(int i=tid;i<499*8;i+=256){
        const int e=i>>3, j=i&7, s=sk[e], d=sk[e+1];
        atomicAdd(&agg1[d*8+j], deg[s]*deg[d]*h1pre[s*8+j]);
    }
    __syncthreads();
    for(int i=tid;i<808;i+=256){ const int j=i&7; agg1[i] = fmaxf(agg1[i]+gcn_b1[j], 0.f); }
    __syncthreads();
    for(int i=tid;i<808;i+=256){ const int n=i>>3; agg2[i] = deg[n]*deg[n]*agg1[i]; }
    __syncthreads();
    for(int i=tid;i<499*8;i+=256){
        const int e=i>>3, j=i&7, s=sk[e], d=sk[e+1];
        atomicAdd(&agg2[d*8+j], deg[s]*deg[d]*agg1[s*8+j]);
    }
    const size_t prow = (size_t)(len-1)*500;
    float vmax = -1e30f;
    for(int i=tid;i<500;i+=256){ const float v = pos[prow+i]*msk[i]; coef[i]=v; vmax=fmaxf(vmax,v); }
    red[tid]=vmax; __syncthreads();           // also orders agg2 atomics
    for(int s=128;s>0;s>>=1){ if(tid<s) red[tid]=fmaxf(red[tid],red[tid+s]); __syncthreads(); }
    const float m = red[0]; __syncthreads();
    float lsum=0.f;
    for(int i=tid;i<500;i+=256){ const float e=__expf(coef[i]-m); coef[i]=e; lsum+=e; }
    red[tid]=lsum; __syncthreads();
    for(int s=128;s>0;s>>=1){ if(tid<s) red[tid]+=red[tid+s]; __syncthreads(); }
    const float inv = 1.f/red[0];
    __syncthreads();
    float v8[8]={0,0,0,0,0,0,0,0}; float ls=0.f;
    for(int i=tid;i<500;i+=256){
        const float ci = coef[i]*inv*msk[i];
        if(ci!=0.f){
            const int n=sk[i]; ls+=ci;
            #pragma unroll
            for(int j=0;j<8;j++) v8[j] += ci*agg2[n*8+j];
        }
    }
    #pragma unroll
    for(int j=0;j<8;j++) atomicAdd(&vec8[j], v8[j]);
    atomicAdd(&sS[0], ls);
    __syncthreads();
    {
        const int o = tid;
        float acc = gcn_b2[o]*sS[0];
        #pragma unroll
        for(int j=0;j<8;j++) acc += vec8[j]*gcn_w2[o*8+j];
        pooled[b*256+o] = acc;
    }
}

// ====== x-part tables: table[combo] = x(skill,answer) @ Wih[:,256:768]^T + bih + bhh ======
__global__ __launch_bounds__(256) void k_table(
    const float* __restrict__ skill_emb, const float* __restrict__ answer_emb,
    const float* __restrict__ wih, const float* __restrict__ bih, const float* __restrict__ bhh,
    float* __restrict__ table)
{
    const int combo = blockIdx.x, tid = threadIdx.x;
    const int sid = combo/3, ans = combo - sid*3;
    __shared__ float sf[256], sg[256];
    sf[tid] = (ans==1) ? skill_emb[(size_t)sid*256+tid] : answer_emb[(size_t)ans*256+tid];
    sg[tid] = (ans==1) ? answer_emb[(size_t)ans*256+tid] : skill_emb[(size_t)sid*256+tid];
    __syncthreads();
    const int o = tid;
    float acc = bih[o] + bhh[o];
    const float* w = wih + (size_t)o*768;
    for(int k=0;k<256;k+=4){
        f32x4 w1v = *(const f32x4*)&w[256+k];
        f32x4 w2v = *(const f32x4*)&w[512+k];
        acc += sf[k]*w1v.x + sf[k+1]*w1v.y + sf[k+2]*w1v.z + sf[k+3]*w1v.w;
        acc += sg[k]*w2v.x + sg[k+1]*w2v.y + sg[k+2]*w2v.z + sg[k+3]*w2v.w;
    }
    table[(size_t)combo*256 + o] = acc;
}

// =============== pooled_proj[b] = pooled[b] @ dg_wih[:, :256]^T  (bf16 64x256) ===============
__global__ __launch_bounds__(256) void k_pooledproj(const float* __restrict__ pooled,
                                                    const float* __restrict__ wih,
                                                    u16* __restrict__ outp)
{
    const int b=blockIdx.x, tid=threadIdx.x;
    __shared__ float p[256];
    p[tid] = pooled[b*256+tid];
    __syncthreads();
    const float* w = wih + (size_t)tid*768;
    float acc=0.f;
    for(int k=0;k<256;k+=4){
        f32x4 wv = *(const f32x4*)&w[k];
        acc += p[k]*wv.x + p[k+1]*wv.y + p[k+2]*wv.z + p[k+3]*wv.w;
    }
    outp[b*256+tid]=f2b(acc);
}

// ====== k_pre: pre[rnn][t][b][c] = table[combo] + proj  (bf16, t-major) ======
// grid (500, 2, 4), block 256.
__global__ __launch_bounds__(256) void k_pre(
    const int* __restrict__ combo_t, const int* __restrict__ sid_t,
    const float* __restrict__ table_dg, const float* __restrict__ table_hg,
    const u16* __restrict__ pooled_proj, const u16* __restrict__ stu_proj,
    u16* __restrict__ pre_dg, u16* __restrict__ pre_hg)
{
    const int t = blockIdx.x, rnn = blockIdx.y, c = threadIdx.x;
    const int b0 = blockIdx.z*16;
    const float* tab = rnn ? table_hg : table_dg;
    u16* outp = rnn ? pre_hg : pre_dg;
    for(int b=b0;b<b0+16;b++){
        const int cmb = combo_t[t*64+b];
        const u16* prow = rnn ? (stu_proj + (size_t)sid_t[t*64+b]*256)
                              : (pooled_proj + (size_t)b*256);
        const float v = tab[(size_t)cmb*256 + c] + b2f(prow[c]);
        outp[((size_t)t*64+b)*256 + c] = f2b(v);
    }
}

// =============== RNN v4: transposed MFMA, LDS-only barrier, cheap epilogue ======
// 8 blocks = (rnn, 16-row group), 8 waves; wave owns output cols [wave*32, +32).
__global__ __launch_bounds__(512) void k_rnn(
    const u16* __restrict__ pre_dg, const u16* __restrict__ pre_hg,
    const float* __restrict__ whh_dg, const float* __restrict__ whh_hg,
    u16* __restrict__ hall_dg, u16* __restrict__ hall_hg)
{
    __shared__ u16 hc[2][8][4][16][8];    // 2 x 8KB, A/B-fragment chunk layout
    const int bid = blockIdx.x;
    const int rnn = bid>>2, grp = bid&3, rb = grp*16;
    const float* W   = rnn ? whh_hg : whh_dg;
    const u16*  pre  = rnn ? pre_hg : pre_dg;
    u16*        out  = rnn ? hall_hg : hall_dg;
    const int tid = threadIdx.x, wave = tid>>6, lane = tid&63;
    const int lm = lane&15, lg = lane>>4;
    const int cb = wave*32;

    // W fragments as A-operand (row = output col), register-resident
    short8 wf[2][8];
    #pragma unroll
    for(int nt=0;nt<2;nt++)
        #pragma unroll
        for(int kk=0;kk<8;kk++)
            wf[nt][kk] = ld8f(W + (size_t)(cb+nt*16+lm)*256 + kk*32 + lg*8);

    for(int i=tid;i<2*8*4*16*8;i+=512) ((u16*)hc)[i]=0;

    const size_t rowoff = (size_t)(rb+lm)*256;
    uint2 pv[2];
    #pragma unroll
    for(int nt=0;nt<2;nt++)
        pv[nt] = *(const uint2*)&pre[rowoff + cb + nt*16 + lg*4];
    __syncthreads();

    int cur = 0;
    for(int t=0;t<500;t++){
        // two independent 4-deep MFMA chains per output tile
        f32x4 a0={0.f,0.f,0.f,0.f}, a1={0.f,0.f,0.f,0.f};
        f32x4 c0={0.f,0.f,0.f,0.f}, c1={0.f,0.f,0.f,0.f};
        #pragma unroll
        for(int kk=0;kk<4;kk++){
            short8 hb = *(const short8*)&hc[cur][kk][lg][lm][0];
            a0 = __builtin_amdgcn_mfma_f32_16x16x32_bf16(wf[0][kk], hb, a0, 0,0,0);
            a1 = __builtin_amdgcn_mfma_f32_16x16x32_bf16(wf[1][kk], hb, a1, 0,0,0);
        }
        #pragma unroll
        for(int kk=4;kk<8;kk++){
            short8 hb = *(const short8*)&hc[cur][kk][lg][lm][0];
            c0 = __builtin_amdgcn_mfma_f32_16x16x32_bf16(wf[0][kk], hb, c0, 0,0,0);
            c1 = __builtin_amdgcn_mfma_f32_16x16x32_bf16(wf[1][kk], hb, c1, 0,0,0);
        }
        // prefetch next step's pre
        uint2 pvn[2];
        {
            const int tn = (t<499)? t+1 : 499;
            const size_t base = (size_t)tn*64*256 + rowoff;
            pvn[0] = *(const uint2*)&pre[base + cb + lg*4];
            pvn[1] = *(const uint2*)&pre[base + cb + 16 + lg*4];
        }
        const f32x4 acc0 = a0+c0, acc1 = a1+c1;
        #pragma unroll
        for(int nt=0;nt<2;nt++){
            const f32x4 a = nt ? acc1 : acc0;
            const unsigned plo = pv[nt].x, phi = pv[nt].y;
            u16 hv[4];
            #pragma unroll
            for(int r=0;r<4;r++){
                const u16 pb = (u16)(((r<2)? plo : phi) >> ((r&1)*16));
                const float v = a[r] + b2f(pb);
                const float e = __expf(2.f*v);
                const float th = 1.f - 2.f*__builtin_amdgcn_rcpf(e+1.f);  // tanh, approx rcp
                hv[r] = f2b_fast(th);
            }
            uint2 pk;
            pk.x = (unsigned)hv[0] | ((unsigned)hv[1]<<16);
            pk.y = (unsigned)hv[2] | ((unsigned)hv[3]<<16);
            *(uint2*)&hc[cur^1][wave][nt*2+(lg>>1)][lm][(lg&1)*4] = pk;
            *(uint2*)&out[(size_t)t*64*256 + rowoff + cb + nt*16 + lg*4] = pk;
        }
        barrier_lds();      // LDS-visibility only: global loads/stores stay in flight
        pv[0]=pvn[0]; pv[1]=pvn[1];
        cur ^= 1;
    }
}

// ====== theta = sigmoid(h_hg@w1^T + h_dg@w2^T + b1 + b2), dual-GEMM fused, bf16 out ======
// grid (250, 4), block 256.  M=32000, N=256, K=256.
__global__ __launch_bounds__(256) void k_theta(
    const u16* __restrict__ Ah, const u16* __restrict__ Ad,
    const float* __restrict__ w1, const float* __restrict__ w2,
    const float* __restrict__ b1, const float* __restrict__ b2,
    u16* __restrict__ theta)
{
    constexpr int BK=32;
    __shared__ u16 AsH[128][BK+8];
    __shared__ u16 AsD[128][BK+8];
    __shared__ u16 BsH[64][BK+8];
    __shared__ u16 BsD[64][BK+8];
    const int tid = threadIdx.x;
    const int bm = blockIdx.x*128, bn = blockIdx.y*64;
    const int wave = tid>>6, lane = tid&63, lm = lane&15, lg = lane>>4;
    const int wm = (wave>>1)*64, wn = (wave&1)*32;
    f32x4 acc[4][2];
    #pragma unroll
    for(int i=0;i<4;i++){ acc[i][0]=(f32x4){0.f,0.f,0.f,0.f}; acc[i][1]=(f32x4){0.f,0.f,0.f,0.f}; }

    const int arow0 = tid>>2, akc0 = (tid&3)*8;
    const int arow1 = arow0 + 64;
    for(int k0=0;k0<256;k0+=BK){
        *(short8*)&AsH[arow0][akc0] = ld8b(Ah + (size_t)(bm+arow0)*256 + k0+akc0);
        *(short8*)&AsH[arow1][akc0] = ld8b(Ah + (size_t)(bm+arow1)*256 + k0+akc0);
        *(short8*)&AsD[arow0][akc0] = ld8b(Ad + (size_t)(bm+arow0)*256 + k0+akc0);
        *(short8*)&AsD[arow1][akc0] = ld8b(Ad + (size_t)(bm+arow1)*256 + k0+akc0);
        *(short8*)&BsH[arow0][akc0] = ld8f(w1 + (size_t)(bn+arow0)*256 + k0+akc0);
        *(short8*)&BsD[arow0][akc0] = ld8f(w2 + (size_t)(bn+arow0)*256 + k0+akc0);
        __syncthreads();
        short8 afH[4], afD[4], bf1[2], bf2[2];
        #pragma unroll
        for(int mt=0;mt<4;mt++){
            afH[mt] = *(const short8*)&AsH[wm+mt*16+lm][lg*8];
            afD[mt] = *(const short8*)&AsD[wm+mt*16+lm][lg*8];
        }
        #pragma unroll
        for(int nt=0;nt<2;nt++){
            bf1[nt] = *(const short8*)&BsH[wn+nt*16+lm][lg*8];
            bf2[nt] = *(const short8*)&BsD[wn+nt*16+lm][lg*8];
        }
        #pragma unroll
        for(int nt=0;nt<2;nt++)
            #pragma unroll
            for(int mt=0;mt<4;mt++){
                acc[mt][nt] = __builtin_amdgcn_mfma_f32_16x16x32_bf16(afH[mt], bf1[nt], acc[mt][nt], 0,0,0);
                acc[mt][nt] = __builtin_amdgcn_mfma_f32_16x16x32_bf16(afD[mt], bf2[nt], acc[mt][nt], 0,0,0);
            }
        __syncthreads();
    }
    #pragma unroll
    for(int nt=0;nt<2;nt++){
        const int col = bn+wn+nt*16+lm;
        const float bb = b1[col]+b2[col];
        #pragma unroll
        for(int mt=0;mt<4;mt++){
            const int row0 = bm+wm+mt*16+lg*4;
            #pragma unroll
            for(int r=0;r<4;r++){
                const float x = acc[mt][nt][r] + bb;
                theta[(size_t)(row0+r)*256 + col] = f2b(1.f/(1.f+__expf(-x)));
            }
        }
    }
}

// =============== final gather: one wave per (b,t), three outputs ===============
__global__ __launch_bounds__(256) void k_out(
    const int* __restrict__ skill,
    const u16* __restrict__ hall_hg, const u16* __restrict__ hall_dg,
    const u16* __restrict__ theta,
    const float* __restrict__ fc_h_w, const float* __restrict__ fc_h_b,
    const float* __restrict__ fc_d_w, const float* __restrict__ fc_d_b,
    const float* __restrict__ fc_e_w, const float* __restrict__ fc_e_b,
    float* __restrict__ outp)
{
    const int tid=threadIdx.x, lane=tid&63;
    const int wid = blockIdx.x*4 + (tid>>6);        // 0..31935
    const int b = wid/499, t = wid - b*499;
    const int ns = skill[b*500 + t + 1];
    float o0=0.f,o1=0.f,o2=0.f,bh=0.f,bd=0.f,be=0.f;
    if(ns != 100){
        const int c = iclamp(ns, 0, 99);
        const size_t r = (size_t)t*64 + b;
        const int k = lane*4;
        short4v hh  = *(const short4v*)&hall_hg[r*256+k];
        short4v hd  = *(const short4v*)&hall_dg[r*256+k];
        short4v th  = *(const short4v*)&theta[r*256+k];
        f32x4 fh  = *(const f32x4*)&fc_h_w[(size_t)c*256+k];
        f32x4 fd  = *(const f32x4*)&fc_d_w[(size_t)c*256+k];
        f32x4 fe1 = *(const f32x4*)&fc_e_w[(size_t)c*512+k];
        f32x4 fe2 = *(const f32x4*)&fc_e_w[(size_t)c*512+256+k];
        #pragma unroll
        for(int j=0;j<4;j++){
            const float hhj=b2f((u16)hh[j]), hdj=b2f((u16)hd[j]), tj=b2f((u16)th[j]);
            o0 += hhj*fh[j];
            o1 += hdj*fd[j];
            o2 += tj*hhj*fe1[j] + (1.f-tj)*hdj*fe2[j];
        }
        #pragma unroll
        for(int off=32;off>0;off>>=1){
            o0 += __shfl_down(o0,off);
            o1 += __shfl_down(o1,off);
            o2 += __shfl_down(o2,off);
        }
        bh=fc_h_b[c]; bd=fc_d_b[c]; be=fc_e_b[c];
    }
    if(lane==0){
        outp[            b*499+t] = (ns==100)?0.f:(o0+bh);
        outp[31936     + b*499+t] = (ns==100)?0.f:(o1+bd);
        outp[2*31936   + b*499+t] = (ns==100)?0.f:(o2+be);
    }
}

// ================================= launch =================================
extern "C" void kernel_launch(void* const* d_in, const int* in_sizes, int n_in,
                              void* d_out, int out_size, void* d_ws, size_t ws_size,
                              hipStream_t stream)
{
    const int* student = (const int*)d_in[0];
    const int* skill   = (const int*)d_in[1];
    const int* answer  = (const int*)d_in[2];
    const float* G        = (const float*)d_in[3];
    const float* skill_emb= (const float*)d_in[4];
    const float* answer_emb=(const float*)d_in[5];
    const float* stu      = (const float*)d_in[6];
    const float* hg_w1    = (const float*)d_in[7];
    const float* hg_b1    = (const float*)d_in[8];
    const float* hg_w2    = (const float*)d_in[9];
    const float* hg_b2    = (const float*)d_in[10];
    const float* gcn_w1   = (const float*)d_in[11];
    const float* gcn_b1   = (const float*)d_in[12];
    const float* gcn_w2   = (const float*)d_in[13];
    const float* gcn_b2   = (const float*)d_in[14];
    const float* w1_w     = (const float*)d_in[15];
    const float* w1_b     = (const float*)d_in[16];
    const float* w2_w     = (const float*)d_in[17];
    const float* w2_b     = (const float*)d_in[18];
    const float* fc_d_w   = (const float*)d_in[19];
    const float* fc_d_b   = (const float*)d_in[20];
    const float* fc_h_w   = (const float*)d_in[21];
    const float* fc_h_b   = (const float*)d_in[22];
    const float* fc_e_w   = (const float*)d_in[23];
    const float* fc_e_b   = (const float*)d_in[24];
    const float* pos      = (const float*)d_in[25];
    const float* dg_wih   = (const float*)d_in[26];
    const float* dg_whh   = (const float*)d_in[27];
    const float* dg_bih   = (const float*)d_in[28];
    const float* dg_bhh   = (const float*)d_in[29];
    const float* hgr_wih  = (const float*)d_in[30];
    const float* hgr_whh  = (const float*)d_in[31];
    const float* hgr_bih  = (const float*)d_in[32];
    const float* hgr_bhh  = (const float*)d_in[33];

    char* ws = (char*)d_ws;
    size_t off = 0;
    auto nxt = [&](size_t bytes)->char*{
        char* r = ws + off;
        off += (bytes + 255) & ~(size_t)255;
        return r;
    };
    float* h1pre      = (float*)nxt(808*4);
    float* pooled     = (float*)nxt(64*256*4);
    float* table_dg   = (float*)nxt(303*256*4);
    float* table_hg   = (float*)nxt(303*256*4);
    u16*   tmpT       = (u16*)  nxt((size_t)256*4096*2);
    u16*   hbuf       = (u16*)  nxt((size_t)4096*256*2);
    u16*   stu_proj   = (u16*)  nxt((size_t)4096*256*2);
    u16*   pooled_proj= (u16*)  nxt(64*256*2);
    int*   combo_t    = (int*)  nxt(32000*4);
    int*   sid_t      = (int*)  nxt(32000*4);
    u16*   Gb         = (u16*)  nxt((size_t)4096*4096*2);   // 33.6 MB; dead after g4
    u16*   hall_dg    = (u16*)  nxt((size_t)32000*256*2);   // 16.4 MB
    u16*   hall_hg    = (u16*)  nxt((size_t)32000*256*2);   // 16.4 MB
    // overlays on Gb (Gb dead before k_pre writes these):
    u16*   pre_dg     = Gb;
    u16*   pre_hg     = Gb + (size_t)32000*256;
    u16*   theta      = pre_dg;                              // pre_dg dead after k_rnn

    // small prep
    k_h1pre<<<8,256,0,stream>>>(skill_emb, gcn_w1, h1pre);
    k_gcn<<<64,256,0,stream>>>(skill, answer, pos, h1pre, gcn_b1, gcn_w2, gcn_b2, pooled);
    k_table<<<303,256,0,stream>>>(skill_emb, answer_emb, dg_wih,  dg_bih,  dg_bhh,  table_dg);
    k_table<<<303,256,0,stream>>>(skill_emb, answer_emb, hgr_wih, hgr_bih, hgr_bhh, table_hg);
    k_idx<<<125,256,0,stream>>>(skill, answer, student, combo_t, sid_t);
    k_cvt<<<8192,256,0,stream>>>(G, Gb);

    // student GCN chain (all 256-block launches)
    gemm64<true ,false,true ,true ><<<dim3(64,4),256,0,stream>>>(stu,  hg_w1, hg_b1, tmpT, 4096,256,256,  256, 4096);
    gemm64<false,true ,false,false><<<dim3(64,4),256,0,stream>>>(Gb,   tmpT,  nullptr, hbuf, 4096,256,4096, 4096, 256);
    gemm64<true ,false,false,true ><<<dim3(64,4),256,0,stream>>>(hbuf, hg_w2, hg_b2, tmpT, 4096,256,256,  256, 4096);
    gemm64<false,false,false,false><<<dim3(64,4),256,0,stream>>>(Gb,   tmpT,  nullptr, hbuf, 4096,256,4096, 4096, 256);
    gemm64<false,false,false,true ><<<dim3(64,4),256,0,stream>>>(hbuf, hgr_wih, nullptr, stu_proj, 4096,256,256, 768, 256);

    k_pooledproj<<<64,256,0,stream>>>(pooled, dg_wih, pooled_proj);

    // fused pre-activation array (t-major bf16) — overwrites Gb (dead)
    k_pre<<<dim3(500,2,4),256,0,stream>>>(combo_t, sid_t, table_dg, table_hg,
                                          pooled_proj, stu_proj, pre_dg, pre_hg);

    // recurrences
    k_rnn<<<8,512,0,stream>>>(pre_dg, pre_hg, dg_whh, hgr_whh, hall_dg, hall_hg);

    // theta + outputs
    k_theta<<<dim3(250,4),256,0,stream>>>(hall_hg, hall_dg, w1_w, w2_w, w1_b, w2_b, theta);
    k_out<<<7984,256,0,stream>>>(skill, hall_hg, hall_dg, theta,
                                 fc_h_w, fc_h_b, fc_d_w, fc_d_b, fc_e_w, fc_e_b,
                                 (float*)d_out);
}